// Round 16
// baseline (335.351 us; speedup 1.0000x reference)
//
#include <hip/hip_runtime.h>
#include <math.h>

typedef __attribute__((ext_vector_type(8))) __bf16 bf16x8;
typedef __attribute__((ext_vector_type(4))) __bf16 bf16x4;
typedef __attribute__((ext_vector_type(4))) float f32x4;

#define TSEQ 2048
#define HDIM 3584
#define NQH  16
#define NKVH 8
#define DH   256
#define WIN  1024
#define QKD  (NQH * DH)   /* 4096 */
#define KVD  (NKVH * DH)  /* 2048 */
#define QLD  8256         /* qkv row stride */
#define OLD  4160         /* o_bf row stride */
#define WOLD 4160         /* WoT row stride */
#define VLD  2112         /* vT row stride */

#define MFMA __builtin_amdgcn_mfma_f32_16x16x32_bf16

__device__ __forceinline__ void gload_lds16(const void* g, void* l) {
  __builtin_amdgcn_global_load_lds(
      (const __attribute__((address_space(1))) void*)g,
      (__attribute__((address_space(3))) void*)l, 16, 0, 0);
}

// ---------------- prep kernels ----------------

__global__ void cvt_bf16_kernel(const float* __restrict__ in,
                                __bf16* __restrict__ out, long n) {
  long i = ((long)blockIdx.x * blockDim.x + threadIdx.x) * 4;
  if (i >= n) return;
  float4 v = *reinterpret_cast<const float4*>(in + i);
  bf16x4 o4;
  o4.x = (__bf16)v.x; o4.y = (__bf16)v.y; o4.z = (__bf16)v.z; o4.w = (__bf16)v.w;
  *reinterpret_cast<bf16x4*>(out + i) = o4;
}

// all 4 weight transposes (fp32 RxC -> bf16 CxR, ld ldo) in one launch
__global__ void transpose_all_kernel(const float* __restrict__ Wq,
                                     const float* __restrict__ Wk,
                                     const float* __restrict__ Wv,
                                     const float* __restrict__ Wo,
                                     __bf16* __restrict__ WqT,
                                     __bf16* __restrict__ WkT,
                                     __bf16* __restrict__ WvT,
                                     __bf16* __restrict__ WoT) {
  __shared__ float tile[64][65];
  int id = blockIdx.x;
  const float* src; __bf16* dst; int R, C, ldo;
  if (id < 3584)      { src = Wq; dst = WqT; R = HDIM; C = QKD; ldo = HDIM; }
  else if (id < 5376) { id -= 3584; src = Wk; dst = WkT; R = HDIM; C = KVD; ldo = HDIM; }
  else if (id < 7168) { id -= 5376; src = Wv; dst = WvT; R = HDIM; C = KVD; ldo = HDIM; }
  else                { id -= 7168; src = Wo; dst = WoT; R = QKD; C = HDIM; ldo = WOLD; }
  const int nbx = C >> 6;
  const int c0 = (id % nbx) * 64, r0 = (id / nbx) * 64;
  const int tid = threadIdx.x;  // 256
#pragma unroll
  for (int it = 0; it < 4; ++it) {
    int f = tid + it * 256;
    int row = f >> 4, c4 = (f & 15) * 4;
    float4 v = *reinterpret_cast<const float4*>(&src[(size_t)(r0 + row) * C + c0 + c4]);
    tile[row][c4] = v.x; tile[row][c4 + 1] = v.y;
    tile[row][c4 + 2] = v.z; tile[row][c4 + 3] = v.w;
  }
  __syncthreads();
#pragma unroll
  for (int it = 0; it < 2; ++it) {
    int s = tid + it * 256;
    int oc = s >> 3, rb = (s & 7) * 8;
    bf16x8 o8;
#pragma unroll
    for (int j = 0; j < 8; ++j) o8[j] = (__bf16)tile[rb + j][oc];
    *reinterpret_cast<bf16x8*>(&dst[(size_t)(c0 + oc) * ldo + r0 + rb]) = o8;
  }
}

// in: R x C bf16 (leading dim ldin) -> out: C x R bf16 (leading dim ldout)
__global__ void transpose_bf16_kernel(const __bf16* __restrict__ in,
                                      __bf16* __restrict__ out, int ldin, int ldout) {
  __shared__ __bf16 tile[32][33];
  const int tx = threadIdx.x, ty = threadIdx.y;
  const int c0 = blockIdx.x * 32, r0 = blockIdx.y * 32;
#pragma unroll
  for (int i = 0; i < 4; ++i)
    tile[ty + i * 8][tx] = in[(size_t)(r0 + ty + i * 8) * ldin + (c0 + tx)];
  __syncthreads();
#pragma unroll
  for (int i = 0; i < 4; ++i)
    out[(size_t)(c0 + ty + i * 8) * ldout + (r0 + tx)] = tile[tx][ty + i * 8];
}

__global__ void rope_table_kernel(const int* __restrict__ positions,
                                  float* __restrict__ ct,
                                  float* __restrict__ st) {
  int i = blockIdx.x * blockDim.x + threadIdx.x;
  if (i >= TSEQ * 128) return;
  int t = i >> 7, j = i & 127;
  float invf = (float)exp((double)(-2 * j) * (9.210340371976184 / 256.0));
  float ang = (float)positions[t] * invf;
  ct[i] = cosf(ang);
  st[i] = sinf(ang);
}

// RoPE over q heads (scale 1/16) and k heads (scale 1); bf16x8-vectorized
__global__ void rope_qk_kernel(__bf16* __restrict__ qkv,
                               const float* __restrict__ ct,
                               const float* __restrict__ st) {
  int i = blockIdx.x * blockDim.x + threadIdx.x;  // TSEQ*24*16
  int jg = (i & 15) * 8;
  int th = i >> 4;
  int t = th / 24;
  int hh = th - t * 24;
  float scale = (hh < 16) ? 0.0625f : 1.0f;
  size_t base = (size_t)t * QLD + ((hh < 16) ? hh * DH : QKD + (hh - 16) * DH) + jg;
  bf16x8 x1 = *reinterpret_cast<const bf16x8*>(qkv + base);
  bf16x8 x2 = *reinterpret_cast<const bf16x8*>(qkv + base + 128);
  const float* cp = ct + (t << 7) + jg;
  const float* sp = st + (t << 7) + jg;
  bf16x8 o1, o2;
#pragma unroll
  for (int e = 0; e < 8; ++e) {
    float c = cp[e], s = sp[e];
    float a = (float)x1[e], b = (float)x2[e];
    o1[e] = (__bf16)((a * c - b * s) * scale);
    o2[e] = (__bf16)((b * c + a * s) * scale);
  }
  *reinterpret_cast<bf16x8*>(qkv + base) = o1;
  *reinterpret_cast<bf16x8*>(qkv + base + 128) = o2;
}

#define BAR __builtin_amdgcn_s_barrier()

// ---------------- QKV GEMM: 256x128 tiles, BK=32, 512 blocks (2/CU) ----------------
// A: M x K bf16 (ld lda). B: N x K bf16 (ld lda). C[m][n] = sum_k A[m][k]B[n][k].
// 8 waves = 4M x 2N, per-wave 64x64. LDS 48KB -> 2 blocks/CU co-resident:
// one block's MFMA overlaps the other's LDS/stage phases (m114 mechanism).
// Swizzle (64B rows): slot ^= (row>>1)&3 on BOTH dma-source and ds_read.

__device__ __forceinline__ void stage32(const __bf16* __restrict__ gbase,
                                        int row0, int lda, int k0,
                                        __bf16* lds_half, int tid) {
  const int row = tid >> 2;          // 0..127
  const int slot = tid & 3;
  const __bf16* g = gbase + (size_t)(row0 + row) * lda + k0 +
                    ((slot ^ ((row >> 1) & 3)) << 3);
  gload_lds16(g, lds_half + tid * 8);
}

__global__ __launch_bounds__(512, 2) void gemmqkv_kernel(
    const __bf16* __restrict__ A, const __bf16* __restrict__ B,
    __bf16* __restrict__ C, int lda, int Klen, int ldc) {
  __shared__ __bf16 lds[2][3][4096];  // [parity][A-h0, A-h1, B][128x32]

  const int per = gridDim.x >> 3;     // 64
  const int wg = (blockIdx.x & 7) * per + (blockIdx.x >> 3);  // XCD swizzle
  const int row0 = (wg & 7) * 256;    // col-major: XCD owns a col band
  const int col0 = (wg >> 3) * 128;

  const int tid = threadIdx.x;
  const int lane = tid & 63, w = tid >> 6;
  const int wr = w >> 1, wc = w & 1;  // 4M x 2N
  const int l15 = lane & 15, lg = lane >> 4;

  const __bf16* Ablk = A + (size_t)row0 * lda;
  const __bf16* Bblk = B + (size_t)col0 * lda;

  f32x4 acc[4][4] = {};
  const int NT = Klen >> 5;

  // per-wave read offsets (element units), swizzled
  int aoff[4], boff[4];
#pragma unroll
  for (int m = 0; m < 4; ++m) {
    int r = wr * 64 + m * 16 + l15;          // 0..255
    int rl = r & 127;
    aoff[m] = (r >> 7) * 4096 + rl * 32 + ((lg ^ ((rl >> 1) & 3)) << 3);
  }
#pragma unroll
  for (int n = 0; n < 4; ++n) {
    int r = wc * 64 + n * 16 + l15;          // 0..127
    boff[n] = 8192 + r * 32 + ((lg ^ ((r >> 1) & 3)) << 3);
  }

  // prologue: tile0 (A both halves + B) -> buf0; tile1 A -> buf1? No: keep
  // simple depth: A(0),B(0)->buf0; A(1) halves -> buf1.
  stage32(Ablk, 0,   lda, 0,  &lds[0][0][0], tid);
  stage32(Ablk, 128, lda, 0,  &lds[0][1][0], tid);
  stage32(Bblk, 0,   lda, 0,  &lds[0][2][0], tid);
  stage32(Ablk, 0,   lda, 32, &lds[1][0][0], tid);
  stage32(Ablk, 128, lda, 32, &lds[1][1][0], tid);
  asm volatile("s_waitcnt vmcnt(2)" ::: "memory");
  BAR;

  for (int t = 0; t < NT; ++t) {
    const int cur = t & 1, nxt = cur ^ 1;
    const __bf16* base = &lds[cur][0][0];

    bf16x8 a[4], b[4];
#pragma unroll
    for (int m = 0; m < 4; ++m) a[m] = *(const bf16x8*)(base + aoff[m]);
#pragma unroll
    for (int n = 0; n < 4; ++n) b[n] = *(const bf16x8*)(base + boff[n]);

    // stage next tile's B into nxt (read last in iter t-1, >=1 BAR ago)
    if (t + 1 < NT) stage32(Bblk, 0, lda, (t + 1) * 32, &lds[nxt][2][0], tid);

    asm volatile("s_waitcnt lgkmcnt(0)" ::: "memory");
    BAR;
    // cur's A region safe to overwrite (all waves' reads retired)
    if (t + 2 < NT) {
      stage32(Ablk, 0,   lda, (t + 2) * 32, &lds[cur][0][0], tid);
      stage32(Ablk, 128, lda, (t + 2) * 32, &lds[cur][1][0], tid);
    }

    __builtin_amdgcn_s_setprio(1);
#pragma unroll
    for (int m = 0; m < 4; ++m)
#pragma unroll
      for (int n = 0; n < 4; ++n)
        acc[m][n] = MFMA(a[m], b[n], acc[m][n], 0, 0, 0);
    __builtin_amdgcn_s_setprio(0);

    // vmcnt(2): oldest-first retirement -> B(t+1) + A(t+1) landed;
    // only A(t+2)'s 2 loads stay in flight.
    if (t + 2 < NT) {
      asm volatile("s_waitcnt vmcnt(2)" ::: "memory");
    } else {
      asm volatile("s_waitcnt vmcnt(0)" ::: "memory");
    }
    BAR;
  }

#pragma unroll
  for (int m = 0; m < 4; ++m)
#pragma unroll
    for (int n = 0; n < 4; ++n)
#pragma unroll
      for (int r = 0; r < 4; ++r) {
        int row = row0 + wr * 64 + m * 16 + lg * 4 + r;
        int col = col0 + wc * 64 + n * 16 + l15;
        C[(size_t)row * ldc + col] = (__bf16)acc[m][n][r];
      }
}

// ---------------- 128x256 lockstep-K GEMM (out-projection, bf16) ----------------

__device__ __forceinline__ void stage_half(const __bf16* __restrict__ gbase,
                                           int row0, int ldg, int k0,
                                           __bf16* lds_half, int tid) {
  const int lane = tid & 63;
  const int w = tid >> 6;
  const int lr = lane >> 3;
  const int swzcol = ((lane & 7) ^ lr) << 3;
  const __bf16* g = gbase + (size_t)(row0 + w * 8 + lr) * ldg + k0 + swzcol;
  __bf16* l = lds_half + w * 512;
  gload_lds16(g, l);
  gload_lds16(g + (size_t)64 * ldg, l + 4096);
}

#define RD_B(DST, BASE, NO)                                         \
  _Pragma("unroll")                                                 \
  for (int n_ = 0; n_ < 2; ++n_) {                                  \
    const __bf16* p_ = (BASE) + (bro + ((NO) + n_) * 16 + l15) * 64;\
    DST[n_][0] = *(const bf16x8*)(p_ + kxa);                        \
    DST[n_][1] = *(const bf16x8*)(p_ + kxb);                        \
  }

__global__ __launch_bounds__(512, 1) void gemm128_kernel(
    const __bf16* __restrict__ A, const __bf16* __restrict__ B,
    float* __restrict__ C, int lda, int Klen, int ldc) {
  __shared__ __bf16 lds[2][3][8192];  // [parity][0=A,1..2=B-halves][128*64]

  const int per = gridDim.x >> 3;
  const int wg = (blockIdx.x & 7) * per + (blockIdx.x >> 3);
  const int row0 = (wg & 15) * 128;
  const int col0 = (wg >> 4) * 256;

  const int tid = threadIdx.x;
  const int lane = tid & 63, w = tid >> 6;
  const int wr = w >> 2, wc = w & 3;   // 2M x 4N
  const int l15 = lane & 15, lg = lane >> 4;
  const int kxa = (lg * 8) ^ ((lane & 7) << 3);
  const int kxb = (32 + lg * 8) ^ ((lane & 7) << 3);
  const int bro = (wc & 1) * 64;

  const __bf16* Ablk = A + (size_t)row0 * lda;
  const __bf16* Bblk = B + (size_t)col0 * lda;

  f32x4 acc[4][4] = {};
  const int NT = Klen >> 6;

  stage_half(Ablk, 0,   lda, 0,  &lds[0][0][0], tid);
  stage_half(Bblk, 0,   lda, 0,  &lds[0][1][0], tid);
  stage_half(Bblk, 128, lda, 0,  &lds[0][2][0], tid);
  stage_half(Ablk, 0,   lda, 64, &lds[1][0][0], tid);
  asm volatile("s_waitcnt vmcnt(2)" ::: "memory");
  BAR;

  bf16x8 a03[4][2], b01[2][2], b23[2][2];

  for (int t = 0; t < NT; ++t) {
    const int cur = t & 1, nxt = cur ^ 1;
    const __bf16* Ah = &lds[cur][0][0];
    const __bf16* Bh = &lds[cur][1 + (wc >> 1)][0];

    {
      const int MO = wr * 4;
#pragma unroll
      for (int m_ = 0; m_ < 4; ++m_) {
        const __bf16* p_ = Ah + ((MO + m_) * 16 + l15) * 64;
        a03[m_][0] = *(const bf16x8*)(p_ + kxa);
        a03[m_][1] = *(const bf16x8*)(p_ + kxb);
      }
    }
    RD_B(b01, Bh, 0);
    RD_B(b23, Bh, 2);

    if (t + 1 < NT) {
      stage_half(Bblk, 0,   lda, (t + 1) * 64, &lds[nxt][1][0], tid);
      stage_half(Bblk, 128, lda, (t + 1) * 64, &lds[nxt][2][0], tid);
    }

    asm volatile("s_waitcnt lgkmcnt(0)" ::: "memory");
    BAR;
    if (t + 2 < NT) stage_half(Ablk, 0, lda, (t + 2) * 64, &lds[cur][0][0], tid);

    __builtin_amdgcn_s_setprio(1);
#pragma unroll
    for (int m_ = 0; m_ < 4; ++m_) {
#pragma unroll
      for (int n_ = 0; n_ < 2; ++n_) {
        acc[m_][n_] = MFMA(a03[m_][0], b01[n_][0], acc[m_][n_], 0, 0, 0);
        acc[m_][n_] = MFMA(a03[m_][1], b01[n_][1], acc[m_][n_], 0, 0, 0);
        acc[m_][n_ + 2] = MFMA(a03[m_][0], b23[n_][0], acc[m_][n_ + 2], 0, 0, 0);
        acc[m_][n_ + 2] = MFMA(a03[m_][1], b23[n_][1], acc[m_][n_ + 2], 0, 0, 0);
      }
    }
    __builtin_amdgcn_s_setprio(0);

    if (t + 2 < NT) {
      asm volatile("s_waitcnt vmcnt(2)" ::: "memory");
    } else {
      asm volatile("s_waitcnt vmcnt(0)" ::: "memory");
    }
    BAR;
  }

#pragma unroll
  for (int m = 0; m < 4; ++m)
#pragma unroll
    for (int n = 0; n < 4; ++n)
#pragma unroll
      for (int r = 0; r < 4; ++r) {
        int row = row0 + wr * 64 + m * 16 + lg * 4 + r;
        int col = col0 + wc * 64 + n * 16 + l15;
        C[(size_t)row * ldc + col] = acc[m][n][r];
      }
}

// ---------------- flash attention: 4-wave blocks, 2 blocks/CU ----------------

__device__ __forceinline__ void attn_stage(const __bf16* __restrict__ kg,
                                           const __bf16* __restrict__ vg,
                                           __bf16* Kd, __bf16* Vd, int tid) {
#pragma unroll
  for (int i = 0; i < 8; ++i) {
    int c = tid + i * 256;
    int krow = c >> 5, kslot = c & 31;
    gload_lds16(kg + (size_t)krow * QLD + ((kslot ^ (krow & 7)) * 8), Kd + c * 8);
    int vrow = c >> 3, vslot = c & 7;
    gload_lds16(vg + (size_t)vrow * VLD + ((vslot ^ (vrow & 7)) * 8), Vd + c * 8);
  }
}

__global__ __launch_bounds__(256, 2) void attn_kernel(
    const __bf16* __restrict__ q, const __bf16* __restrict__ k,
    const __bf16* __restrict__ vt, __bf16* __restrict__ o) {
  __shared__ __bf16 Klds[64][256];
  __shared__ __bf16 Vlds[256][64];
  __shared__ __bf16 Plds[4][16][72];

  const int tid = threadIdx.x;
  const int wave = tid >> 6;
  const int lane = tid & 63;
  const int l16 = lane & 15;
  const int lg = lane >> 4;
  const int h = blockIdx.x;
  const int qh = 2 * h + (blockIdx.y & 1);
  const int q0 = (31 - (int)(blockIdx.y >> 1)) << 6;
  const int qr = q0 + wave * 16;

  const __bf16* kg0 = k + (size_t)h * DH;
  const __bf16* vg0 = vt + (size_t)(h * DH) * VLD;

  int t_lo = q0 - (WIN - 1);
  if (t_lo < 0) t_lo = 0;
  t_lo &= ~63;
  const int NTile = ((q0 - t_lo) >> 6) + 1;

  bf16x8 qf[8];
  {
    const __bf16* qp = q + (size_t)(qr + l16) * QLD + qh * DH + lg * 8;
#pragma unroll
    for (int ds = 0; ds < 8; ++ds)
      qf[ds] = *reinterpret_cast<const bf16x8*>(qp + ds * 32);
  }

  f32x4 accO[16] = {};
  float l_run[4] = {0.f, 0.f, 0.f, 0.f};

  for (int it = 0; it < NTile; ++it) {
    const int t0 = t_lo + it * 64;

    attn_stage(kg0 + (size_t)t0 * QLD, vg0 + t0, &Klds[0][0], &Vlds[0][0], tid);
    asm volatile("s_waitcnt vmcnt(0)" ::: "memory");
    __builtin_amdgcn_s_barrier();

    f32x4 accS[4] = {};
    __builtin_amdgcn_s_setprio(1);
#pragma unroll
    for (int ds = 0; ds < 8; ++ds)
#pragma unroll
      for (int nt = 0; nt < 4; ++nt) {
        int row = nt * 16 + l16;
        int slot = (4 * ds + lg) ^ (l16 & 7);
        bf16x8 kf = *reinterpret_cast<const bf16x8*>(&Klds[0][0] + row * 256 + slot * 8);
        accS[nt] = MFMA(qf[ds], kf, accS[nt], 0, 0, 0);
      }
    __builtin_amdgcn_s_setprio(0);

    float rs[4] = {0.f, 0.f, 0.f, 0.f};
#pragma unroll
    for (int nt = 0; nt < 4; ++nt) {
      int key = t0 + nt * 16 + l16;
#pragma unroll
      for (int r = 0; r < 4; ++r) {
        int row = qr + lg * 4 + r;
        float t = __expf(accS[nt][r] * 0.04f);
        float p = __expf(-100.0f / (t + 1.0f));
        bool valid = (key <= row) && (row - key < WIN);
        p = valid ? p : 0.f;
        rs[r] += p;
        Plds[wave][lg * 4 + r][nt * 16 + l16] = (__bf16)p;
      }
    }
#pragma unroll
    for (int off = 1; off < 16; off <<= 1)
#pragma unroll
      for (int r = 0; r < 4; ++r)
        rs[r] += __shfl_xor(rs[r], off);
#pragma unroll
    for (int r = 0; r < 4; ++r)
      l_run[r] += rs[r];

    __builtin_amdgcn_s_setprio(1);
#pragma unroll
    for (int ks = 0; ks < 2; ++ks) {
      bf16x8 pa = *reinterpret_cast<const bf16x8*>(&Plds[wave][l16][ks * 32 + lg * 8]);
#pragma unroll
      for (int nt2 = 0; nt2 < 16; ++nt2) {
        int row = nt2 * 16 + l16;
        int slot = (4 * ks + lg) ^ (l16 & 7);
        bf16x8 vb = *reinterpret_cast<const bf16x8*>(&Vlds[0][0] + row * 64 + slot * 8);
        accO[nt2] = MFMA(pa, vb, accO[nt2], 0, 0, 0);
      }
    }
    __builtin_amdgcn_s_setprio(0);
    __builtin_amdgcn_s_barrier();
  }

#pragma unroll
  for (int r = 0; r < 4; ++r) {
    float inv_l = 1.f / l_run[r];
    int row = qr + lg * 4 + r;
#pragma unroll
    for (int nt2 = 0; nt2 < 16; ++nt2)
      o[(size_t)row * OLD + qh * DH + nt2 * 16 + l16] = (__bf16)(accO[nt2][r] * inv_l);
  }
}

// ---------------- launcher ----------------

extern "C" void kernel_launch(void* const* d_in, const int* in_sizes, int n_in,
                              void* d_out, int out_size, void* d_ws, size_t ws_size,
                              hipStream_t stream) {
  const float* hs = (const float*)d_in[0];
  const float* Wq = (const float*)d_in[1];
  const float* Wk = (const float*)d_in[2];
  const float* Wv = (const float*)d_in[3];
  const float* Wo = (const float*)d_in[4];
  const int* positions = (const int*)d_in[5];
  float* out = (float*)d_out;

  char* ws = (char*)d_ws;
  const size_t SZ_HS  = (size_t)TSEQ * HDIM * 2;
  const size_t SZ_WQT = (size_t)QKD * HDIM * 2;
  const size_t SZ_WKT = (size_t)KVD * HDIM * 2;
  const size_t SZ_WOT = (size_t)HDIM * WOLD * 2;
  const size_t SZ_QKV = (size_t)TSEQ * QLD * 2;
  const size_t SZ_O   = (size_t)TSEQ * OLD * 2;
  const size_t SZ_VT  = (size_t)KVD * VLD * 2;
  const size_t SZ_TBL = (size_t)TSEQ * 128 * 4;

  __bf16* hs_bf = (__bf16*)ws; ws += SZ_HS;
  __bf16* WqT   = (__bf16*)ws; ws += SZ_WQT;   // WqT/WkT/WvT contiguous -> fused B
  __bf16* WkT   = (__bf16*)ws; ws += SZ_WKT;
  __bf16* WvT   = (__bf16*)ws; ws += SZ_WKT;
  __bf16* WoT   = (__bf16*)ws; ws += SZ_WOT;
  __bf16* qkv   = (__bf16*)ws; ws += SZ_QKV;
  __bf16* o_bf  = (__bf16*)ws; ws += SZ_O;
  __bf16* vt_bf = (__bf16*)ws; ws += SZ_VT;
  float*  cost  = (float*)ws;  ws += SZ_TBL;
  float*  sint  = (float*)ws;  ws += SZ_TBL;
  if ((size_t)(ws - (char*)d_ws) > ws_size) return;

  // prep
  cvt_bf16_kernel<<<(TSEQ * HDIM) / 1024, 256, 0, stream>>>(hs, hs_bf, (long)TSEQ * HDIM);
  transpose_all_kernel<<<10752, 256, 0, stream>>>(Wq, Wk, Wv, Wo, WqT, WkT, WvT, WoT);
  rope_table_kernel<<<(TSEQ * 128) / 256, 256, 0, stream>>>(positions, cost, sint);

  // fused QKV projection: 256x128 tiles, 512 blocks (2/CU co-resident)
  gemmqkv_kernel<<<512, 512, 0, stream>>>(hs_bf, WqT, qkv, HDIM, HDIM, QLD);

  // RoPE q+k merged (vectorized); V transpose
  rope_qk_kernel<<<(TSEQ * 24 * 16) / 256, 256, 0, stream>>>(qkv, cost, sint);
  transpose_bf16_kernel<<<dim3(KVD / 32, TSEQ / 32), dim3(32, 8), 0, stream>>>(qkv + QKD + KVD, vt_bf, QLD, VLD);

  // attention: 512 blocks, 2/CU; grid.x = kv-head = XCD
  attn_kernel<<<dim3(NKVH, 64), 256, 0, stream>>>(qkv, qkv + QKD, vt_bf, o_bf);

  // output projection: 128x256 tiles, 224 blocks, lockstep K, fp32 direct out
  gemm128_kernel<<<224, 512, 0, stream>>>(o_bf, WoT, out, OLD, QKD, HDIM);
}

// Round 17
// 304.506 us; speedup vs baseline: 1.1013x; 1.1013x over previous
//
#include <hip/hip_runtime.h>
#include <math.h>

typedef __attribute__((ext_vector_type(8))) __bf16 bf16x8;
typedef __attribute__((ext_vector_type(4))) __bf16 bf16x4;
typedef __attribute__((ext_vector_type(4))) float f32x4;

#define TSEQ 2048
#define HDIM 3584
#define NQH  16
#define NKVH 8
#define DH   256
#define WIN  1024
#define QKD  (NQH * DH)   /* 4096 */
#define KVD  (NKVH * DH)  /* 2048 */
#define QLD  8256         /* qkv row stride */
#define OLD  4160         /* o_bf row stride */
#define WOLD 4160         /* WoT row stride */
#define VLD  2112         /* vT row stride */

#define MFMA __builtin_amdgcn_mfma_f32_16x16x32_bf16

__device__ __forceinline__ void gload_lds16(const void* g, void* l) {
  __builtin_amdgcn_global_load_lds(
      (const __attribute__((address_space(1))) void*)g,
      (__attribute__((address_space(3))) void*)l, 16, 0, 0);
}

// ---------------- prep kernels ----------------

__global__ void cvt_bf16_kernel(const float* __restrict__ in,
                                __bf16* __restrict__ out, long n) {
  long i = ((long)blockIdx.x * blockDim.x + threadIdx.x) * 4;
  if (i >= n) return;
  float4 v = *reinterpret_cast<const float4*>(in + i);
  bf16x4 o4;
  o4.x = (__bf16)v.x; o4.y = (__bf16)v.y; o4.z = (__bf16)v.z; o4.w = (__bf16)v.w;
  *reinterpret_cast<bf16x4*>(out + i) = o4;
}

// all 4 weight transposes (fp32 RxC -> bf16 CxR, ld ldo) in one launch
__global__ void transpose_all_kernel(const float* __restrict__ Wq,
                                     const float* __restrict__ Wk,
                                     const float* __restrict__ Wv,
                                     const float* __restrict__ Wo,
                                     __bf16* __restrict__ WqT,
                                     __bf16* __restrict__ WkT,
                                     __bf16* __restrict__ WvT,
                                     __bf16* __restrict__ WoT) {
  __shared__ float tile[64][65];
  int id = blockIdx.x;
  const float* src; __bf16* dst; int R, C, ldo;
  if (id < 3584)      { src = Wq; dst = WqT; R = HDIM; C = QKD; ldo = HDIM; }
  else if (id < 5376) { id -= 3584; src = Wk; dst = WkT; R = HDIM; C = KVD; ldo = HDIM; }
  else if (id < 7168) { id -= 5376; src = Wv; dst = WvT; R = HDIM; C = KVD; ldo = HDIM; }
  else                { id -= 7168; src = Wo; dst = WoT; R = QKD; C = HDIM; ldo = WOLD; }
  const int nbx = C >> 6;
  const int c0 = (id % nbx) * 64, r0 = (id / nbx) * 64;
  const int tid = threadIdx.x;  // 256
#pragma unroll
  for (int it = 0; it < 4; ++it) {
    int f = tid + it * 256;
    int row = f >> 4, c4 = (f & 15) * 4;
    float4 v = *reinterpret_cast<const float4*>(&src[(size_t)(r0 + row) * C + c0 + c4]);
    tile[row][c4] = v.x; tile[row][c4 + 1] = v.y;
    tile[row][c4 + 2] = v.z; tile[row][c4 + 3] = v.w;
  }
  __syncthreads();
#pragma unroll
  for (int it = 0; it < 2; ++it) {
    int s = tid + it * 256;
    int oc = s >> 3, rb = (s & 7) * 8;
    bf16x8 o8;
#pragma unroll
    for (int j = 0; j < 8; ++j) o8[j] = (__bf16)tile[rb + j][oc];
    *reinterpret_cast<bf16x8*>(&dst[(size_t)(c0 + oc) * ldo + r0 + rb]) = o8;
  }
}

// in: R x C bf16 (leading dim ldin) -> out: C x R bf16 (leading dim ldout)
__global__ void transpose_bf16_kernel(const __bf16* __restrict__ in,
                                      __bf16* __restrict__ out, int ldin, int ldout) {
  __shared__ __bf16 tile[32][33];
  const int tx = threadIdx.x, ty = threadIdx.y;
  const int c0 = blockIdx.x * 32, r0 = blockIdx.y * 32;
#pragma unroll
  for (int i = 0; i < 4; ++i)
    tile[ty + i * 8][tx] = in[(size_t)(r0 + ty + i * 8) * ldin + (c0 + tx)];
  __syncthreads();
#pragma unroll
  for (int i = 0; i < 4; ++i)
    out[(size_t)(c0 + ty + i * 8) * ldout + (r0 + tx)] = tile[tx][ty + i * 8];
}

__global__ void rope_table_kernel(const int* __restrict__ positions,
                                  float* __restrict__ ct,
                                  float* __restrict__ st) {
  int i = blockIdx.x * blockDim.x + threadIdx.x;
  if (i >= TSEQ * 128) return;
  int t = i >> 7, j = i & 127;
  float invf = (float)exp((double)(-2 * j) * (9.210340371976184 / 256.0));
  float ang = (float)positions[t] * invf;
  ct[i] = cosf(ang);
  st[i] = sinf(ang);
}

// RoPE over q heads (scale 1/16) and k heads (scale 1); bf16x8-vectorized
__global__ void rope_qk_kernel(__bf16* __restrict__ qkv,
                               const float* __restrict__ ct,
                               const float* __restrict__ st) {
  int i = blockIdx.x * blockDim.x + threadIdx.x;  // TSEQ*24*16
  int jg = (i & 15) * 8;
  int th = i >> 4;
  int t = th / 24;
  int hh = th - t * 24;
  float scale = (hh < 16) ? 0.0625f : 1.0f;
  size_t base = (size_t)t * QLD + ((hh < 16) ? hh * DH : QKD + (hh - 16) * DH) + jg;
  bf16x8 x1 = *reinterpret_cast<const bf16x8*>(qkv + base);
  bf16x8 x2 = *reinterpret_cast<const bf16x8*>(qkv + base + 128);
  const float* cp = ct + (t << 7) + jg;
  const float* sp = st + (t << 7) + jg;
  bf16x8 o1, o2;
#pragma unroll
  for (int e = 0; e < 8; ++e) {
    float c = cp[e], s = sp[e];
    float a = (float)x1[e], b = (float)x2[e];
    o1[e] = (__bf16)((a * c - b * s) * scale);
    o2[e] = (__bf16)((b * c + a * s) * scale);
  }
  *reinterpret_cast<bf16x8*>(qkv + base) = o1;
  *reinterpret_cast<bf16x8*>(qkv + base + 128) = o2;
}

// ---------------- 256x256 8-phase GEMM, 2 K-tiles/iter (48% util) ----------------

__device__ __forceinline__ void stage_half(const __bf16* __restrict__ gbase,
                                           int row0, int ldg, int k0,
                                           __bf16* lds_half, int tid) {
  const int lane = tid & 63;
  const int w = tid >> 6;
  const int lr = lane >> 3;                    // row&7 within half
  const int swzcol = ((lane & 7) ^ lr) << 3;   // pre-swizzled source column
  const __bf16* g = gbase + (size_t)(row0 + w * 8 + lr) * ldg + k0 + swzcol;
  __bf16* l = lds_half + w * 512;              // wave-uniform dest (elements)
  gload_lds16(g, l);
  gload_lds16(g + (size_t)64 * ldg, l + 4096);
}

#define BAR __builtin_amdgcn_s_barrier()

#define RD_A(DST, BASE, MO)                                         \
  _Pragma("unroll")                                                 \
  for (int m_ = 0; m_ < 4; ++m_) {                                  \
    const __bf16* p_ = (BASE) + (((MO) + m_) * 16 + l15) * 64;      \
    DST[m_][0] = *(const bf16x8*)(p_ + kxa);                        \
    DST[m_][1] = *(const bf16x8*)(p_ + kxb);                        \
  }

#define RD_B(DST, BASE, NO)                                         \
  _Pragma("unroll")                                                 \
  for (int n_ = 0; n_ < 2; ++n_) {                                  \
    const __bf16* p_ = (BASE) + (bro + ((NO) + n_) * 16 + l15) * 64;\
    DST[n_][0] = *(const bf16x8*)(p_ + kxa);                        \
    DST[n_][1] = *(const bf16x8*)(p_ + kxb);                        \
  }

#define MQUAD(AF, BF, MO, NO)                                          \
  __builtin_amdgcn_s_setprio(1);                                       \
  _Pragma("unroll")                                                    \
  for (int m_ = 0; m_ < 4; ++m_)                                       \
    _Pragma("unroll")                                                  \
    for (int n_ = 0; n_ < 2; ++n_) {                                   \
      acc[(MO) + m_][(NO) + n_] =                                      \
          MFMA(AF[m_][0], BF[n_][0], acc[(MO) + m_][(NO) + n_], 0, 0, 0); \
      acc[(MO) + m_][(NO) + n_] =                                      \
          MFMA(AF[m_][1], BF[n_][1], acc[(MO) + m_][(NO) + n_], 0, 0, 0); \
    }                                                                  \
  __builtin_amdgcn_s_setprio(0);

__global__ __launch_bounds__(512, 2) void gemm256_kernel(
    const __bf16* __restrict__ A, const __bf16* __restrict__ B,
    __bf16* __restrict__ C, int lda, int Klen, int ldc, int nrc) {
  __shared__ __bf16 lds[2][2][2][8192];  // [tile-parity][A=0/B=1][half][128*64]

  const int nwg = gridDim.x;
  const int per = nwg >> 3;
  const int wg = (blockIdx.x & 7) * per + (blockIdx.x >> 3);  // XCD chunk swizzle
  const int rem = wg % nrc;
  const int row0 = (rem & 7) * 256;        // col-major decode: XCD owns col-band
  const int col0 = (rem >> 3) * 256;
  __bf16* Cs = C;

  const int tid = threadIdx.x;
  const int lane = tid & 63, w = tid >> 6;
  const int wr = w >> 2, wc = w & 3;
  const int l15 = lane & 15, lg = lane >> 4;
  const int kxa = (lg * 8) ^ ((lane & 7) << 3);
  const int kxb = (32 + lg * 8) ^ ((lane & 7) << 3);
  const int bro = (wc & 1) * 64;

  const __bf16* Ablk = A + (size_t)row0 * lda;
  const __bf16* Bblk = B + (size_t)col0 * lda;

  const __bf16* Ae = &lds[0][0][wr][0];
  const __bf16* Be = &lds[0][1][wc >> 1][0];
  const __bf16* Ao = &lds[1][0][wr][0];
  const __bf16* Bo = &lds[1][1][wc >> 1][0];

  f32x4 acc[8][4] = {};
  const int NT = Klen >> 6;
  const int NI = NT >> 1;

  // prologue: tile0 all halves -> buf0; tile1 A halves -> buf1
  stage_half(Ablk, 0,   lda, 0,  &lds[0][0][0][0], tid);
  stage_half(Ablk, 128, lda, 0,  &lds[0][0][1][0], tid);
  stage_half(Bblk, 0,   lda, 0,  &lds[0][1][0][0], tid);
  stage_half(Bblk, 128, lda, 0,  &lds[0][1][1][0], tid);
  stage_half(Ablk, 0,   lda, 64, &lds[1][0][0][0], tid);
  stage_half(Ablk, 128, lda, 64, &lds[1][0][1][0], tid);
  asm volatile("s_waitcnt vmcnt(4)" ::: "memory");
  BAR;

  bf16x8 a03[4][2], a47[4][2], b01[2][2], b23[2][2];

  for (int j = 0; j < NI; ++j) {
    const int e = 2 * j, o = 2 * j + 1;
    const bool last = (j == NI - 1);

    RD_A(a03, Ae, 0);
    RD_B(b01, Be, 0);
    stage_half(Bblk, 0, lda, o * 64, &lds[1][1][0][0], tid);
    asm volatile("s_waitcnt lgkmcnt(8)" ::: "memory");
    BAR; MQUAD(a03, b01, 0, 0); BAR;

    RD_A(a47, Ae, 4);
    stage_half(Bblk, 128, lda, o * 64, &lds[1][1][1][0], tid);
    BAR; MQUAD(a47, b01, 4, 0); BAR;

    RD_B(b23, Be, 2);
    if (!last) stage_half(Ablk, 0, lda, (e + 2) * 64, &lds[0][0][0][0], tid);
    BAR; MQUAD(a47, b23, 4, 2); BAR;

    if (!last) {
      stage_half(Ablk, 128, lda, (e + 2) * 64, &lds[0][0][1][0], tid);
      asm volatile("s_waitcnt vmcnt(4)" ::: "memory");
    } else {
      asm volatile("s_waitcnt vmcnt(0)" ::: "memory");
    }
    BAR; MQUAD(a03, b23, 0, 2); BAR;

    RD_A(a03, Ao, 0);
    RD_B(b01, Bo, 0);
    if (!last) stage_half(Bblk, 0, lda, (e + 2) * 64, &lds[0][1][0][0], tid);
    asm volatile("s_waitcnt lgkmcnt(8)" ::: "memory");
    BAR; MQUAD(a03, b01, 0, 0); BAR;

    RD_A(a47, Ao, 4);
    if (!last) stage_half(Bblk, 128, lda, (e + 2) * 64, &lds[0][1][1][0], tid);
    BAR; MQUAD(a47, b01, 4, 0); BAR;

    RD_B(b23, Bo, 2);
    if (!last) stage_half(Ablk, 0, lda, (o + 2) * 64, &lds[1][0][0][0], tid);
    BAR; MQUAD(a47, b23, 4, 2); BAR;

    if (!last) {
      stage_half(Ablk, 128, lda, (o + 2) * 64, &lds[1][0][1][0], tid);
      asm volatile("s_waitcnt vmcnt(4)" ::: "memory");
    }
    BAR; MQUAD(a03, b23, 0, 2); BAR;
  }

#pragma unroll
  for (int m = 0; m < 8; ++m)
#pragma unroll
    for (int n = 0; n < 4; ++n)
#pragma unroll
      for (int r = 0; r < 4; ++r) {
        int row = row0 + wr * 128 + m * 16 + lg * 4 + r;
        int col = col0 + wc * 64 + n * 16 + l15;
        Cs[(size_t)row * ldc + col] = (__bf16)acc[m][n][r];
      }
}

// ---------------- 128x256 lockstep-K GEMM (out-projection) ----------------
// Grid 16x14 = 224 blocks, all on the same K schedule (no split-K).
// 8 waves = 2Mx4N, each 64x64 out. Per K-tile: 16 ds_reads -> stage
// B(t+1)->nxt -> lgkmcnt(0) -> BAR -> stage A(t+2)->cur -> 32 MFMA ->
// vmcnt(2) -> BAR.
__global__ __launch_bounds__(512, 1) void gemm128_kernel(
    const __bf16* __restrict__ A, const __bf16* __restrict__ B,
    float* __restrict__ C, int lda, int Klen, int ldc) {
  __shared__ __bf16 lds[2][3][8192];  // [parity][0=A,1..2=B-halves][128*64]

  const int per = gridDim.x >> 3;
  const int wg = (blockIdx.x & 7) * per + (blockIdx.x >> 3);
  const int row0 = (wg & 15) * 128;
  const int col0 = (wg >> 4) * 256;

  const int tid = threadIdx.x;
  const int lane = tid & 63, w = tid >> 6;
  const int wr = w >> 2, wc = w & 3;   // 2M x 4N
  const int l15 = lane & 15, lg = lane >> 4;
  const int kxa = (lg * 8) ^ ((lane & 7) << 3);
  const int kxb = (32 + lg * 8) ^ ((lane & 7) << 3);
  const int bro = (wc & 1) * 64;

  const __bf16* Ablk = A + (size_t)row0 * lda;
  const __bf16* Bblk = B + (size_t)col0 * lda;

  f32x4 acc[4][4] = {};
  const int NT = Klen >> 6;

  // prologue: A(0),B(0) -> buf0; A(1) -> buf1
  stage_half(Ablk, 0,   lda, 0,  &lds[0][0][0], tid);
  stage_half(Bblk, 0,   lda, 0,  &lds[0][1][0], tid);
  stage_half(Bblk, 128, lda, 0,  &lds[0][2][0], tid);
  stage_half(Ablk, 0,   lda, 64, &lds[1][0][0], tid);
  asm volatile("s_waitcnt vmcnt(2)" ::: "memory");
  BAR;

  bf16x8 a03[4][2], b01[2][2], b23[2][2];

  for (int t = 0; t < NT; ++t) {
    const int cur = t & 1, nxt = cur ^ 1;
    const __bf16* Ah = &lds[cur][0][0];
    const __bf16* Bh = &lds[cur][1 + (wc >> 1)][0];

    {
      const int MO = wr * 4;  // fragment row base within 128 = wr*64
#pragma unroll
      for (int m_ = 0; m_ < 4; ++m_) {
        const __bf16* p_ = Ah + ((MO + m_) * 16 + l15) * 64;
        a03[m_][0] = *(const bf16x8*)(p_ + kxa);
        a03[m_][1] = *(const bf16x8*)(p_ + kxb);
      }
    }
    RD_B(b01, Bh, 0);
    RD_B(b23, Bh, 2);

    if (t + 1 < NT) {
      stage_half(Bblk, 0,   lda, (t + 1) * 64, &lds[nxt][1][0], tid);
      stage_half(Bblk, 128, lda, (t + 1) * 64, &lds[nxt][2][0], tid);
    }

    asm volatile("s_waitcnt lgkmcnt(0)" ::: "memory");
    BAR;
    if (t + 2 < NT) stage_half(Ablk, 0, lda, (t + 2) * 64, &lds[cur][0][0], tid);

    __builtin_amdgcn_s_setprio(1);
#pragma unroll
    for (int m_ = 0; m_ < 4; ++m_) {
#pragma unroll
      for (int n_ = 0; n_ < 2; ++n_) {
        acc[m_][n_] = MFMA(a03[m_][0], b01[n_][0], acc[m_][n_], 0, 0, 0);
        acc[m_][n_] = MFMA(a03[m_][1], b01[n_][1], acc[m_][n_], 0, 0, 0);
        acc[m_][n_ + 2] = MFMA(a03[m_][0], b23[n_][0], acc[m_][n_ + 2], 0, 0, 0);
        acc[m_][n_ + 2] = MFMA(a03[m_][1], b23[n_][1], acc[m_][n_ + 2], 0, 0, 0);
      }
    }
    __builtin_amdgcn_s_setprio(0);

    if (t + 2 < NT) {
      asm volatile("s_waitcnt vmcnt(2)" ::: "memory");
    } else {
      asm volatile("s_waitcnt vmcnt(0)" ::: "memory");
    }
    BAR;
  }

#pragma unroll
  for (int m = 0; m < 4; ++m)
#pragma unroll
    for (int n = 0; n < 4; ++n)
#pragma unroll
      for (int r = 0; r < 4; ++r) {
        int row = row0 + wr * 64 + m * 16 + lg * 4 + r;
        int col = col0 + wc * 64 + n * 16 + l15;
        C[(size_t)row * ldc + col] = acc[m][n][r];
      }
}

// ---------------- flash attention: 4-wave blocks, 2 blocks/CU ----------------
// grid = (8 kv-heads, 64) -> id%8 = kv-head = XCD (K/V L2-affine).
// blockIdx.y: bit0 = q-head parity, bits1+ = q-tile (reversed, LPT).
// 256 thr = 4 waves x 16 q-rows = 64 rows of ONE q-head; 2 blocks/CU.
// Fixed-max softmax (|s|<=50): p = exp(-100/(e^{.04x}+1)), no rescale.

__device__ __forceinline__ void attn_stage(const __bf16* __restrict__ kg,
                                           const __bf16* __restrict__ vg,
                                           __bf16* Kd, __bf16* Vd, int tid) {
#pragma unroll
  for (int i = 0; i < 8; ++i) {
    int c = tid + i * 256;
    int krow = c >> 5, kslot = c & 31;             // K: [64 keys][256 d]
    gload_lds16(kg + (size_t)krow * QLD + ((kslot ^ (krow & 7)) * 8), Kd + c * 8);
    int vrow = c >> 3, vslot = c & 7;              // V: [256 d][64 keys]
    gload_lds16(vg + (size_t)vrow * VLD + ((vslot ^ (vrow & 7)) * 8), Vd + c * 8);
  }
}

__global__ __launch_bounds__(256, 2) void attn_kernel(
    const __bf16* __restrict__ q, const __bf16* __restrict__ k,
    const __bf16* __restrict__ vt, __bf16* __restrict__ o) {
  __shared__ __bf16 Klds[64][256];   // [key][d], slot-swizzled
  __shared__ __bf16 Vlds[256][64];   // [d][key], slot-swizzled
  __shared__ __bf16 Plds[4][16][72]; // [wave][row][key+pad]

  const int tid = threadIdx.x;
  const int wave = tid >> 6;
  const int lane = tid & 63;
  const int l16 = lane & 15;
  const int lg = lane >> 4;
  const int h = blockIdx.x;                      // kv-head == XCD (id%8)
  const int qh = 2 * h + (blockIdx.y & 1);
  const int q0 = (31 - (int)(blockIdx.y >> 1)) << 6;  // LPT: big windows first
  const int qr = q0 + wave * 16;

  const __bf16* kg0 = k + (size_t)h * DH;
  const __bf16* vg0 = vt + (size_t)(h * DH) * VLD;

  int t_lo = q0 - (WIN - 1);
  if (t_lo < 0) t_lo = 0;
  t_lo &= ~63;
  const int NTile = ((q0 - t_lo) >> 6) + 1;

  bf16x8 qf[8];
  {
    const __bf16* qp = q + (size_t)(qr + l16) * QLD + qh * DH + lg * 8;
#pragma unroll
    for (int ds = 0; ds < 8; ++ds)
      qf[ds] = *reinterpret_cast<const bf16x8*>(qp + ds * 32);
  }

  f32x4 accO[16] = {};
  float l_run[4] = {0.f, 0.f, 0.f, 0.f};

  for (int it = 0; it < NTile; ++it) {
    const int t0 = t_lo + it * 64;

    attn_stage(kg0 + (size_t)t0 * QLD, vg0 + t0, &Klds[0][0], &Vlds[0][0], tid);
    asm volatile("s_waitcnt vmcnt(0)" ::: "memory");
    __builtin_amdgcn_s_barrier();

    // QK^T
    f32x4 accS[4] = {};
    __builtin_amdgcn_s_setprio(1);
#pragma unroll
    for (int ds = 0; ds < 8; ++ds)
#pragma unroll
      for (int nt = 0; nt < 4; ++nt) {
        int row = nt * 16 + l16;
        int slot = (4 * ds + lg) ^ (l16 & 7);
        bf16x8 kf = *reinterpret_cast<const bf16x8*>(&Klds[0][0] + row * 256 + slot * 8);
        accS[nt] = MFMA(qf[ds], kf, accS[nt], 0, 0, 0);
      }
    __builtin_amdgcn_s_setprio(0);

    // softcap+exp fixed-max, mask, P -> LDS, row-sum
    float rs[4] = {0.f, 0.f, 0.f, 0.f};
#pragma unroll
    for (int nt = 0; nt < 4; ++nt) {
      int key = t0 + nt * 16 + l16;
#pragma unroll
      for (int r = 0; r < 4; ++r) {
        int row = qr + lg * 4 + r;
        float t = __expf(accS[nt][r] * 0.04f);
        float p = __expf(-100.0f / (t + 1.0f));
        bool valid = (key <= row) && (row - key < WIN);
        p = valid ? p : 0.f;
        rs[r] += p;
        Plds[wave][lg * 4 + r][nt * 16 + l16] = (__bf16)p;
      }
    }
#pragma unroll
    for (int off = 1; off < 16; off <<= 1)
#pragma unroll
      for (int r = 0; r < 4; ++r)
        rs[r] += __shfl_xor(rs[r], off);
#pragma unroll
    for (int r = 0; r < 4; ++r)
      l_run[r] += rs[r];

    // PV
    __builtin_amdgcn_s_setprio(1);
#pragma unroll
    for (int ks = 0; ks < 2; ++ks) {
      bf16x8 pa = *reinterpret_cast<const bf16x8*>(&Plds[wave][l16][ks * 32 + lg * 8]);
#pragma unroll
      for (int nt2 = 0; nt2 < 16; ++nt2) {
        int row = nt2 * 16 + l16;
        int slot = (4 * ks + lg) ^ (l16 & 7);
        bf16x8 vb = *reinterpret_cast<const bf16x8*>(&Vlds[0][0] + row * 64 + slot * 8);
        accO[nt2] = MFMA(pa, vb, accO[nt2], 0, 0, 0);
      }
    }
    __builtin_amdgcn_s_setprio(0);
    __builtin_amdgcn_s_barrier();  // all reads done before next tile's DMA
  }

#pragma unroll
  for (int r = 0; r < 4; ++r) {
    float inv_l = 1.f / l_run[r];
    int row = qr + lg * 4 + r;
#pragma unroll
    for (int nt2 = 0; nt2 < 16; ++nt2)
      o[(size_t)row * OLD + qh * DH + nt2 * 16 + l16] = (__bf16)(accO[nt2][r] * inv_l);
  }
}

// ---------------- launcher ----------------

extern "C" void kernel_launch(void* const* d_in, const int* in_sizes, int n_in,
                              void* d_out, int out_size, void* d_ws, size_t ws_size,
                              hipStream_t stream) {
  const float* hs = (const float*)d_in[0];
  const float* Wq = (const float*)d_in[1];
  const float* Wk = (const float*)d_in[2];
  const float* Wv = (const float*)d_in[3];
  const float* Wo = (const float*)d_in[4];
  const int* positions = (const int*)d_in[5];
  float* out = (float*)d_out;

  char* ws = (char*)d_ws;
  const size_t SZ_HS  = (size_t)TSEQ * HDIM * 2;
  const size_t SZ_WQT = (size_t)QKD * HDIM * 2;
  const size_t SZ_WKT = (size_t)KVD * HDIM * 2;
  const size_t SZ_WOT = (size_t)HDIM * WOLD * 2;
  const size_t SZ_QKV = (size_t)TSEQ * QLD * 2;
  const size_t SZ_O   = (size_t)TSEQ * OLD * 2;
  const size_t SZ_VT  = (size_t)KVD * VLD * 2;
  const size_t SZ_TBL = (size_t)TSEQ * 128 * 4;

  __bf16* hs_bf = (__bf16*)ws; ws += SZ_HS;
  __bf16* WqT   = (__bf16*)ws; ws += SZ_WQT;   // WqT/WkT/WvT contiguous -> fused B
  __bf16* WkT   = (__bf16*)ws; ws += SZ_WKT;
  __bf16* WvT   = (__bf16*)ws; ws += SZ_WKT;
  __bf16* WoT   = (__bf16*)ws; ws += SZ_WOT;
  __bf16* qkv   = (__bf16*)ws; ws += SZ_QKV;
  __bf16* o_bf  = (__bf16*)ws; ws += SZ_O;
  __bf16* vt_bf = (__bf16*)ws; ws += SZ_VT;
  float*  cost  = (float*)ws;  ws += SZ_TBL;
  float*  sint  = (float*)ws;  ws += SZ_TBL;
  if ((size_t)(ws - (char*)d_ws) > ws_size) return;

  // prep
  cvt_bf16_kernel<<<(TSEQ * HDIM) / 1024, 256, 0, stream>>>(hs, hs_bf, (long)TSEQ * HDIM);
  transpose_all_kernel<<<10752, 256, 0, stream>>>(Wq, Wk, Wv, Wo, WqT, WkT, WvT, WoT);
  rope_table_kernel<<<(TSEQ * 128) / 256, 256, 0, stream>>>(positions, cost, sint);

  // fused QKV projection: M=2048, N=8192, K=3584 -> 256 blocks (1/CU)
  gemm256_kernel<<<256, 512, 0, stream>>>(hs_bf, WqT, qkv, HDIM, HDIM, QLD, 256);

  // RoPE q+k merged (vectorized); V transpose
  rope_qk_kernel<<<(TSEQ * 24 * 16) / 256, 256, 0, stream>>>(qkv, cost, sint);
  transpose_bf16_kernel<<<dim3(KVD / 32, TSEQ / 32), dim3(32, 8), 0, stream>>>(qkv + QKD + KVD, vt_bf, QLD, VLD);

  // attention: 512 blocks, 2/CU; grid.x = kv-head = XCD
  attn_kernel<<<dim3(NKVH, 64), 256, 0, stream>>>(qkv, qkv + QKD, vt_bf, o_bf);

  // output projection: 128x256 tiles, 224 blocks, lockstep K, fp32 direct out
  gemm128_kernel<<<224, 512, 0, stream>>>(o_bf, WoT, out, OLD, QKD, HDIM);
}

// Round 18
// 287.215 us; speedup vs baseline: 1.1676x; 1.0602x over previous
//
#include <hip/hip_runtime.h>
#include <math.h>

typedef __attribute__((ext_vector_type(8))) __bf16 bf16x8;
typedef __attribute__((ext_vector_type(4))) __bf16 bf16x4;
typedef __attribute__((ext_vector_type(4))) float f32x4;

#define TSEQ 2048
#define HDIM 3584
#define NQH  16
#define NKVH 8
#define DH   256
#define WIN  1024
#define QKD  (NQH * DH)   /* 4096 */
#define KVD  (NKVH * DH)  /* 2048 */
#define QLD  8256         /* qkv row stride */
#define OLD  4160         /* o_bf row stride */
#define WOLD 4160         /* WoT row stride */
#define VLD  2112         /* vT row stride */

#define MFMA __builtin_amdgcn_mfma_f32_16x16x32_bf16

__device__ __forceinline__ void gload_lds16(const void* g, void* l) {
  __builtin_amdgcn_global_load_lds(
      (const __attribute__((address_space(1))) void*)g,
      (__attribute__((address_space(3))) void*)l, 16, 0, 0);
}

// ---------------- prep: weight transposes + hs cvt, one launch ----------------
// blocks [0,10752): transpose fp32 RxC -> bf16 CxR (64x64 tiles)
// blocks [10752,14336): hs fp32 -> bf16 (2048 elems/block)
__global__ void prep_kernel(const float* __restrict__ hs,
                            const float* __restrict__ Wq,
                            const float* __restrict__ Wk,
                            const float* __restrict__ Wv,
                            const float* __restrict__ Wo,
                            __bf16* __restrict__ hs_bf,
                            __bf16* __restrict__ WqT,
                            __bf16* __restrict__ WkT,
                            __bf16* __restrict__ WvT,
                            __bf16* __restrict__ WoT) {
  __shared__ float tile[64][65];
  int id = blockIdx.x;
  const int tid = threadIdx.x;  // 256
  if (id >= 10752) {            // hs convert
    long base = (long)(id - 10752) * 2048 + tid * 8;
    float4 v0 = *reinterpret_cast<const float4*>(hs + base);
    float4 v1 = *reinterpret_cast<const float4*>(hs + base + 4);
    bf16x8 o8;
    o8[0] = (__bf16)v0.x; o8[1] = (__bf16)v0.y; o8[2] = (__bf16)v0.z; o8[3] = (__bf16)v0.w;
    o8[4] = (__bf16)v1.x; o8[5] = (__bf16)v1.y; o8[6] = (__bf16)v1.z; o8[7] = (__bf16)v1.w;
    *reinterpret_cast<bf16x8*>(hs_bf + base) = o8;
    return;
  }
  const float* src; __bf16* dst; int C, ldo;
  if (id < 3584)      { src = Wq; dst = WqT; C = QKD; ldo = HDIM; }
  else if (id < 5376) { id -= 3584; src = Wk; dst = WkT; C = KVD; ldo = HDIM; }
  else if (id < 7168) { id -= 5376; src = Wv; dst = WvT; C = KVD; ldo = HDIM; }
  else                { id -= 7168; src = Wo; dst = WoT; C = HDIM; ldo = WOLD; }
  const int nbx = C >> 6;
  const int c0 = (id % nbx) * 64, r0 = (id / nbx) * 64;
#pragma unroll
  for (int it = 0; it < 4; ++it) {
    int f = tid + it * 256;
    int row = f >> 4, c4 = (f & 15) * 4;
    float4 v = *reinterpret_cast<const float4*>(&src[(size_t)(r0 + row) * C + c0 + c4]);
    tile[row][c4] = v.x; tile[row][c4 + 1] = v.y;
    tile[row][c4 + 2] = v.z; tile[row][c4 + 3] = v.w;
  }
  __syncthreads();
#pragma unroll
  for (int it = 0; it < 2; ++it) {
    int s = tid + it * 256;
    int oc = s >> 3, rb = (s & 7) * 8;
    bf16x8 o8;
#pragma unroll
    for (int j = 0; j < 8; ++j) o8[j] = (__bf16)tile[rb + j][oc];
    *reinterpret_cast<bf16x8*>(&dst[(size_t)(c0 + oc) * ldo + r0 + rb]) = o8;
  }
}

__global__ void rope_table_kernel(const int* __restrict__ positions,
                                  float* __restrict__ ct,
                                  float* __restrict__ st) {
  int i = blockIdx.x * blockDim.x + threadIdx.x;
  if (i >= TSEQ * 128) return;
  int t = i >> 7, j = i & 127;
  float invf = (float)exp((double)(-2 * j) * (9.210340371976184 / 256.0));
  float ang = (float)positions[t] * invf;
  ct[i] = cosf(ang);
  st[i] = sinf(ang);
}

// ---------------- 256x256 8-phase GEMM + fused rope/vT epilogue ----------------
// Each block owns one head (col0>>8): 0-15 q (rope, x1/16), 16-23 k (rope),
// 24-31 v (write V^T directly). Epilogue round-trips the C-tile through the
// dead staging LDS.

__device__ __forceinline__ void stage_half(const __bf16* __restrict__ gbase,
                                           int row0, int ldg, int k0,
                                           __bf16* lds_half, int tid) {
  const int lane = tid & 63;
  const int w = tid >> 6;
  const int lr = lane >> 3;                    // row&7 within half
  const int swzcol = ((lane & 7) ^ lr) << 3;   // pre-swizzled source column
  const __bf16* g = gbase + (size_t)(row0 + w * 8 + lr) * ldg + k0 + swzcol;
  __bf16* l = lds_half + w * 512;              // wave-uniform dest (elements)
  gload_lds16(g, l);
  gload_lds16(g + (size_t)64 * ldg, l + 4096);
}

#define BAR __builtin_amdgcn_s_barrier()

#define RD_A(DST, BASE, MO)                                         \
  _Pragma("unroll")                                                 \
  for (int m_ = 0; m_ < 4; ++m_) {                                  \
    const __bf16* p_ = (BASE) + (((MO) + m_) * 16 + l15) * 64;      \
    DST[m_][0] = *(const bf16x8*)(p_ + kxa);                        \
    DST[m_][1] = *(const bf16x8*)(p_ + kxb);                        \
  }

#define RD_B(DST, BASE, NO)                                         \
  _Pragma("unroll")                                                 \
  for (int n_ = 0; n_ < 2; ++n_) {                                  \
    const __bf16* p_ = (BASE) + (bro + ((NO) + n_) * 16 + l15) * 64;\
    DST[n_][0] = *(const bf16x8*)(p_ + kxa);                        \
    DST[n_][1] = *(const bf16x8*)(p_ + kxb);                        \
  }

#define MQUAD(AF, BF, MO, NO)                                          \
  __builtin_amdgcn_s_setprio(1);                                       \
  _Pragma("unroll")                                                    \
  for (int m_ = 0; m_ < 4; ++m_)                                       \
    _Pragma("unroll")                                                  \
    for (int n_ = 0; n_ < 2; ++n_) {                                   \
      acc[(MO) + m_][(NO) + n_] =                                      \
          MFMA(AF[m_][0], BF[n_][0], acc[(MO) + m_][(NO) + n_], 0, 0, 0); \
      acc[(MO) + m_][(NO) + n_] =                                      \
          MFMA(AF[m_][1], BF[n_][1], acc[(MO) + m_][(NO) + n_], 0, 0, 0); \
    }                                                                  \
  __builtin_amdgcn_s_setprio(0);

#define STG(p, ab, h) (lds + (p) * 32768 + (ab) * 16384 + (h) * 8192)

__global__ __launch_bounds__(512, 1) void gemm256_kernel(
    const __bf16* __restrict__ A, const __bf16* __restrict__ B,
    __bf16* __restrict__ C, __bf16* __restrict__ vt,
    const float* __restrict__ ct, const float* __restrict__ st,
    int lda, int Klen, int ldc, int nrc) {
  __shared__ __bf16 lds[67584];  // staging 64K elems; epilogue up to 256x264

  const int nwg = gridDim.x;
  const int per = nwg >> 3;
  const int wg = (blockIdx.x & 7) * per + (blockIdx.x >> 3);  // XCD chunk swizzle
  const int rem = wg % nrc;
  const int row0 = (rem & 7) * 256;        // col-major decode: XCD owns col-band
  const int col0 = (rem >> 3) * 256;

  const int tid = threadIdx.x;
  const int lane = tid & 63, w = tid >> 6;
  const int wr = w >> 2, wc = w & 3;
  const int l15 = lane & 15, lg = lane >> 4;
  const int kxa = (lg * 8) ^ ((lane & 7) << 3);
  const int kxb = (32 + lg * 8) ^ ((lane & 7) << 3);
  const int bro = (wc & 1) * 64;

  const __bf16* Ablk = A + (size_t)row0 * lda;
  const __bf16* Bblk = B + (size_t)col0 * lda;

  const __bf16* Ae = STG(0, 0, wr);
  const __bf16* Be = STG(0, 1, wc >> 1);
  const __bf16* Ao = STG(1, 0, wr);
  const __bf16* Bo = STG(1, 1, wc >> 1);

  f32x4 acc[8][4] = {};
  const int NT = Klen >> 6;
  const int NI = NT >> 1;

  // prologue: tile0 all halves -> buf0; tile1 A halves -> buf1
  stage_half(Ablk, 0,   lda, 0,  STG(0, 0, 0), tid);
  stage_half(Ablk, 128, lda, 0,  STG(0, 0, 1), tid);
  stage_half(Bblk, 0,   lda, 0,  STG(0, 1, 0), tid);
  stage_half(Bblk, 128, lda, 0,  STG(0, 1, 1), tid);
  stage_half(Ablk, 0,   lda, 64, STG(1, 0, 0), tid);
  stage_half(Ablk, 128, lda, 64, STG(1, 0, 1), tid);
  asm volatile("s_waitcnt vmcnt(4)" ::: "memory");
  BAR;

  bf16x8 a03[4][2], a47[4][2], b01[2][2], b23[2][2];

  for (int j = 0; j < NI; ++j) {
    const int e = 2 * j, o = 2 * j + 1;
    const bool last = (j == NI - 1);

    RD_A(a03, Ae, 0);
    RD_B(b01, Be, 0);
    stage_half(Bblk, 0, lda, o * 64, STG(1, 1, 0), tid);
    asm volatile("s_waitcnt lgkmcnt(8)" ::: "memory");
    BAR; MQUAD(a03, b01, 0, 0); BAR;

    RD_A(a47, Ae, 4);
    stage_half(Bblk, 128, lda, o * 64, STG(1, 1, 1), tid);
    BAR; MQUAD(a47, b01, 4, 0); BAR;

    RD_B(b23, Be, 2);
    if (!last) stage_half(Ablk, 0, lda, (e + 2) * 64, STG(0, 0, 0), tid);
    BAR; MQUAD(a47, b23, 4, 2); BAR;

    if (!last) {
      stage_half(Ablk, 128, lda, (e + 2) * 64, STG(0, 0, 1), tid);
      asm volatile("s_waitcnt vmcnt(4)" ::: "memory");
    } else {
      asm volatile("s_waitcnt vmcnt(0)" ::: "memory");
    }
    BAR; MQUAD(a03, b23, 0, 2); BAR;

    RD_A(a03, Ao, 0);
    RD_B(b01, Bo, 0);
    if (!last) stage_half(Bblk, 0, lda, (e + 2) * 64, STG(0, 1, 0), tid);
    asm volatile("s_waitcnt lgkmcnt(8)" ::: "memory");
    BAR; MQUAD(a03, b01, 0, 0); BAR;

    RD_A(a47, Ao, 4);
    if (!last) stage_half(Bblk, 128, lda, (e + 2) * 64, STG(0, 1, 1), tid);
    BAR; MQUAD(a47, b01, 4, 0); BAR;

    RD_B(b23, Bo, 2);
    if (!last) stage_half(Ablk, 0, lda, (o + 2) * 64, STG(1, 0, 0), tid);
    BAR; MQUAD(a47, b23, 4, 2); BAR;

    if (!last) {
      stage_half(Ablk, 128, lda, (o + 2) * 64, STG(1, 0, 1), tid);
      asm volatile("s_waitcnt vmcnt(4)" ::: "memory");
    }
    BAR; MQUAD(a03, b23, 0, 2); BAR;
  }

  // ---- fused epilogue (staging LDS is dead after final BAR) ----
  const int head = col0 >> 8;
  if (head < 24) {
    // q/k: rope via (d, d+128) pairing across waves
    const float scale = (head < 16) ? 0.0625f : 1.0f;
#pragma unroll
    for (int m = 0; m < 8; ++m)
#pragma unroll
      for (int n = 0; n < 4; ++n)
#pragma unroll
        for (int r = 0; r < 4; ++r) {
          int rw = wr * 128 + m * 16 + lg * 4 + r;
          int cl = wc * 64 + n * 16 + l15;
          lds[rw * 256 + cl] = (__bf16)acc[m][n][r];
        }
    __syncthreads();
#pragma unroll
    for (int it8 = 0; it8 < 8; ++it8) {
      int g = it8 * 512 + tid;           // 256 rows x 16 d-groups
      int rw = g >> 4, d0 = (g & 15) * 8;
      bf16x8 x1 = *reinterpret_cast<const bf16x8*>(&lds[rw * 256 + d0]);
      bf16x8 x2 = *reinterpret_cast<const bf16x8*>(&lds[rw * 256 + 128 + d0]);
      int t = row0 + rw;
      const float* cp = ct + t * 128 + d0;
      const float* sp = st + t * 128 + d0;
      bf16x8 o1, o2;
#pragma unroll
      for (int e2 = 0; e2 < 8; ++e2) {
        float c = cp[e2], s = sp[e2];
        float a = (float)x1[e2], b = (float)x2[e2];
        o1[e2] = (__bf16)((a * c - b * s) * scale);
        o2[e2] = (__bf16)((b * c + a * s) * scale);
      }
      *reinterpret_cast<bf16x8*>(&C[(size_t)t * ldc + col0 + d0]) = o1;
      *reinterpret_cast<bf16x8*>(&C[(size_t)t * ldc + col0 + 128 + d0]) = o2;
    }
  } else {
    // v: write V^T directly (store tile transposed in LDS, [256][264])
#pragma unroll
    for (int m = 0; m < 8; ++m)
#pragma unroll
      for (int n = 0; n < 4; ++n)
#pragma unroll
        for (int r = 0; r < 4; ++r) {
          int rw = wr * 128 + m * 16 + lg * 4 + r;
          int cl = wc * 64 + n * 16 + l15;
          lds[cl * 264 + rw] = (__bf16)acc[m][n][r];
        }
    __syncthreads();
    const int vbase = (head - 24) * 256;
#pragma unroll
    for (int it16 = 0; it16 < 16; ++it16) {
      int g = it16 * 512 + tid;          // 256 d x 32 row-groups
      int d = g >> 5, rg = (g & 31) * 8;
      bf16x8 v8 = *reinterpret_cast<const bf16x8*>(&lds[d * 264 + rg]);
      *reinterpret_cast<bf16x8*>(&vt[(size_t)(vbase + d) * VLD + row0 + rg]) = v8;
    }
  }
}

// ---------------- 128x256 lockstep-K GEMM (out-projection) ----------------
__global__ __launch_bounds__(512, 1) void gemm128_kernel(
    const __bf16* __restrict__ A, const __bf16* __restrict__ B,
    float* __restrict__ C, int lda, int Klen, int ldc) {
  __shared__ __bf16 lds[2][3][8192];  // [parity][0=A,1..2=B-halves][128*64]

  const int per = gridDim.x >> 3;
  const int wg = (blockIdx.x & 7) * per + (blockIdx.x >> 3);
  const int row0 = (wg & 15) * 128;
  const int col0 = (wg >> 4) * 256;

  const int tid = threadIdx.x;
  const int lane = tid & 63, w = tid >> 6;
  const int wr = w >> 2, wc = w & 3;   // 2M x 4N
  const int l15 = lane & 15, lg = lane >> 4;
  const int kxa = (lg * 8) ^ ((lane & 7) << 3);
  const int kxb = (32 + lg * 8) ^ ((lane & 7) << 3);
  const int bro = (wc & 1) * 64;

  const __bf16* Ablk = A + (size_t)row0 * lda;
  const __bf16* Bblk = B + (size_t)col0 * lda;

  f32x4 acc[4][4] = {};
  const int NT = Klen >> 6;

  stage_half(Ablk, 0,   lda, 0,  &lds[0][0][0], tid);
  stage_half(Bblk, 0,   lda, 0,  &lds[0][1][0], tid);
  stage_half(Bblk, 128, lda, 0,  &lds[0][2][0], tid);
  stage_half(Ablk, 0,   lda, 64, &lds[1][0][0], tid);
  asm volatile("s_waitcnt vmcnt(2)" ::: "memory");
  BAR;

  bf16x8 a03[4][2], b01[2][2], b23[2][2];

  for (int t = 0; t < NT; ++t) {
    const int cur = t & 1, nxt = cur ^ 1;
    const __bf16* Ah = &lds[cur][0][0];
    const __bf16* Bh = &lds[cur][1 + (wc >> 1)][0];

    {
      const int MO = wr * 4;
#pragma unroll
      for (int m_ = 0; m_ < 4; ++m_) {
        const __bf16* p_ = Ah + ((MO + m_) * 16 + l15) * 64;
        a03[m_][0] = *(const bf16x8*)(p_ + kxa);
        a03[m_][1] = *(const bf16x8*)(p_ + kxb);
      }
    }
    RD_B(b01, Bh, 0);
    RD_B(b23, Bh, 2);

    if (t + 1 < NT) {
      stage_half(Bblk, 0,   lda, (t + 1) * 64, &lds[nxt][1][0], tid);
      stage_half(Bblk, 128, lda, (t + 1) * 64, &lds[nxt][2][0], tid);
    }

    asm volatile("s_waitcnt lgkmcnt(0)" ::: "memory");
    BAR;
    if (t + 2 < NT) stage_half(Ablk, 0, lda, (t + 2) * 64, &lds[cur][0][0], tid);

    __builtin_amdgcn_s_setprio(1);
#pragma unroll
    for (int m_ = 0; m_ < 4; ++m_) {
#pragma unroll
      for (int n_ = 0; n_ < 2; ++n_) {
        acc[m_][n_] = MFMA(a03[m_][0], b01[n_][0], acc[m_][n_], 0, 0, 0);
        acc[m_][n_] = MFMA(a03[m_][1], b01[n_][1], acc[m_][n_], 0, 0, 0);
        acc[m_][n_ + 2] = MFMA(a03[m_][0], b23[n_][0], acc[m_][n_ + 2], 0, 0, 0);
        acc[m_][n_ + 2] = MFMA(a03[m_][1], b23[n_][1], acc[m_][n_ + 2], 0, 0, 0);
      }
    }
    __builtin_amdgcn_s_setprio(0);

    if (t + 2 < NT) {
      asm volatile("s_waitcnt vmcnt(2)" ::: "memory");
    } else {
      asm volatile("s_waitcnt vmcnt(0)" ::: "memory");
    }
    BAR;
  }

#pragma unroll
  for (int m = 0; m < 4; ++m)
#pragma unroll
    for (int n = 0; n < 4; ++n)
#pragma unroll
      for (int r = 0; r < 4; ++r) {
        int row = row0 + wr * 64 + m * 16 + lg * 4 + r;
        int col = col0 + wc * 64 + n * 16 + l15;
        C[(size_t)row * ldc + col] = acc[m][n][r];
      }
}

// ---------------- flash attention: 4-wave blocks, 2 blocks/CU ----------------
__device__ __forceinline__ void attn_stage(const __bf16* __restrict__ kg,
                                           const __bf16* __restrict__ vg,
                                           __bf16* Kd, __bf16* Vd, int tid) {
#pragma unroll
  for (int i = 0; i < 8; ++i) {
    int c = tid + i * 256;
    int krow = c >> 5, kslot = c & 31;             // K: [64 keys][256 d]
    gload_lds16(kg + (size_t)krow * QLD + ((kslot ^ (krow & 7)) * 8), Kd + c * 8);
    int vrow = c >> 3, vslot = c & 7;              // V: [256 d][64 keys]
    gload_lds16(vg + (size_t)vrow * VLD + ((vslot ^ (vrow & 7)) * 8), Vd + c * 8);
  }
}

__global__ __launch_bounds__(256, 2) void attn_kernel(
    const __bf16* __restrict__ q, const __bf16* __restrict__ k,
    const __bf16* __restrict__ vt, __bf16* __restrict__ o) {
  __shared__ __bf16 Klds[64][256];   // [key][d], slot-swizzled
  __shared__ __bf16 Vlds[256][64];   // [d][key], slot-swizzled
  __shared__ __bf16 Plds[4][16][72]; // [wave][row][key+pad]

  const int tid = threadIdx.x;
  const int wave = tid >> 6;
  const int lane = tid & 63;
  const int l16 = lane & 15;
  const int lg = lane >> 4;
  const int h = blockIdx.x;                      // kv-head == XCD (id%8)
  const int qh = 2 * h + (blockIdx.y & 1);
  const int q0 = (31 - (int)(blockIdx.y >> 1)) << 6;  // LPT: big windows first
  const int qr = q0 + wave * 16;

  const __bf16* kg0 = k + (size_t)h * DH;
  const __bf16* vg0 = vt + (size_t)(h * DH) * VLD;

  int t_lo = q0 - (WIN - 1);
  if (t_lo < 0) t_lo = 0;
  t_lo &= ~63;
  const int NTile = ((q0 - t_lo) >> 6) + 1;

  bf16x8 qf[8];
  {
    const __bf16* qp = q + (size_t)(qr + l16) * QLD + qh * DH + lg * 8;
#pragma unroll
    for (int ds = 0; ds < 8; ++ds)
      qf[ds] = *reinterpret_cast<const bf16x8*>(qp + ds * 32);
  }

  f32x4 accO[16] = {};
  float l_run[4] = {0.f, 0.f, 0.f, 0.f};

  for (int it = 0; it < NTile; ++it) {
    const int t0 = t_lo + it * 64;

    attn_stage(kg0 + (size_t)t0 * QLD, vg0 + t0, &Klds[0][0], &Vlds[0][0], tid);
    asm volatile("s_waitcnt vmcnt(0)" ::: "memory");
    __builtin_amdgcn_s_barrier();

    // QK^T
    f32x4 accS[4] = {};
    __builtin_amdgcn_s_setprio(1);
#pragma unroll
    for (int ds = 0; ds < 8; ++ds)
#pragma unroll
      for (int nt = 0; nt < 4; ++nt) {
        int row = nt * 16 + l16;
        int slot = (4 * ds + lg) ^ (l16 & 7);
        bf16x8 kf = *reinterpret_cast<const bf16x8*>(&Klds[0][0] + row * 256 + slot * 8);
        accS[nt] = MFMA(qf[ds], kf, accS[nt], 0, 0, 0);
      }
    __builtin_amdgcn_s_setprio(0);

    // softcap+exp fixed-max, mask, P -> LDS, row-sum
    float rs[4] = {0.f, 0.f, 0.f, 0.f};
#pragma unroll
    for (int nt = 0; nt < 4; ++nt) {
      int key = t0 + nt * 16 + l16;
#pragma unroll
      for (int r = 0; r < 4; ++r) {
        int row = qr + lg * 4 + r;
        float t = __expf(accS[nt][r] * 0.04f);
        float p = __expf(-100.0f / (t + 1.0f));
        bool valid = (key <= row) && (row - key < WIN);
        p = valid ? p : 0.f;
        rs[r] += p;
        Plds[wave][lg * 4 + r][nt * 16 + l16] = (__bf16)p;
      }
    }
#pragma unroll
    for (int off = 1; off < 16; off <<= 1)
#pragma unroll
      for (int r = 0; r < 4; ++r)
        rs[r] += __shfl_xor(rs[r], off);
#pragma unroll
    for (int r = 0; r < 4; ++r)
      l_run[r] += rs[r];

    // PV
    __builtin_amdgcn_s_setprio(1);
#pragma unroll
    for (int ks = 0; ks < 2; ++ks) {
      bf16x8 pa = *reinterpret_cast<const bf16x8*>(&Plds[wave][l16][ks * 32 + lg * 8]);
#pragma unroll
      for (int nt2 = 0; nt2 < 16; ++nt2) {
        int row = nt2 * 16 + l16;
        int slot = (4 * ks + lg) ^ (l16 & 7);
        bf16x8 vb = *reinterpret_cast<const bf16x8*>(&Vlds[0][0] + row * 64 + slot * 8);
        accO[nt2] = MFMA(pa, vb, accO[nt2], 0, 0, 0);
      }
    }
    __builtin_amdgcn_s_setprio(0);
    __builtin_amdgcn_s_barrier();  // all reads done before next tile's DMA
  }

#pragma unroll
  for (int r = 0; r < 4; ++r) {
    float inv_l = 1.f / l_run[r];
    int row = qr + lg * 4 + r;
#pragma unroll
    for (int nt2 = 0; nt2 < 16; ++nt2)
      o[(size_t)row * OLD + qh * DH + nt2 * 16 + l16] = (__bf16)(accO[nt2][r] * inv_l);
  }
}

// ---------------- launcher ----------------

extern "C" void kernel_launch(void* const* d_in, const int* in_sizes, int n_in,
                              void* d_out, int out_size, void* d_ws, size_t ws_size,
                              hipStream_t stream) {
  const float* hs = (const float*)d_in[0];
  const float* Wq = (const float*)d_in[1];
  const float* Wk = (const float*)d_in[2];
  const float* Wv = (const float*)d_in[3];
  const float* Wo = (const float*)d_in[4];
  const int* positions = (const int*)d_in[5];
  float* out = (float*)d_out;

  char* ws = (char*)d_ws;
  const size_t SZ_HS  = (size_t)TSEQ * HDIM * 2;
  const size_t SZ_WQT = (size_t)QKD * HDIM * 2;
  const size_t SZ_WKT = (size_t)KVD * HDIM * 2;
  const size_t SZ_WOT = (size_t)HDIM * WOLD * 2;
  const size_t SZ_QKV = (size_t)TSEQ * QLD * 2;
  const size_t SZ_O   = (size_t)TSEQ * OLD * 2;
  const size_t SZ_VT  = (size_t)KVD * VLD * 2;
  const size_t SZ_TBL = (size_t)TSEQ * 128 * 4;

  __bf16* hs_bf = (__bf16*)ws; ws += SZ_HS;
  __bf16* WqT   = (__bf16*)ws; ws += SZ_WQT;   // WqT/WkT/WvT contiguous -> fused B
  __bf16* WkT   = (__bf16*)ws; ws += SZ_WKT;
  __bf16* WvT   = (__bf16*)ws; ws += SZ_WKT;
  __bf16* WoT   = (__bf16*)ws; ws += SZ_WOT;
  __bf16* qkv   = (__bf16*)ws; ws += SZ_QKV;
  __bf16* o_bf  = (__bf16*)ws; ws += SZ_O;
  __bf16* vt_bf = (__bf16*)ws; ws += SZ_VT;
  float*  cost  = (float*)ws;  ws += SZ_TBL;
  float*  sint  = (float*)ws;  ws += SZ_TBL;
  if ((size_t)(ws - (char*)d_ws) > ws_size) return;

  // prep: weight transposes + hs cvt (one launch) + rope tables
  prep_kernel<<<14336, 256, 0, stream>>>(hs, Wq, Wk, Wv, Wo, hs_bf,
                                         WqT, WkT, WvT, WoT);
  rope_table_kernel<<<(TSEQ * 128) / 256, 256, 0, stream>>>(positions, cost, sint);

  // fused QKV projection + rope(q,k) + V^T epilogue: 256 blocks (1/CU)
  gemm256_kernel<<<256, 512, 0, stream>>>(hs_bf, WqT, qkv, vt_bf, cost, sint,
                                          HDIM, HDIM, QLD, 256);

  // attention: 512 blocks, 2/CU; grid.x = kv-head = XCD
  attn_kernel<<<dim3(NKVH, 64), 256, 0, stream>>>(qkv, qkv + QKD, vt_bf, o_bf);

  // output projection: 128x256 tiles, 224 blocks, lockstep K, fp32 direct out
  gemm128_kernel<<<224, 512, 0, stream>>>(o_bf, WoT, out, OLD, QKD, HDIM);
}

// Round 19
// 284.577 us; speedup vs baseline: 1.1784x; 1.0093x over previous
//
#include <hip/hip_runtime.h>
#include <math.h>

typedef __attribute__((ext_vector_type(8))) __bf16 bf16x8;
typedef __attribute__((ext_vector_type(4))) __bf16 bf16x4;
typedef __attribute__((ext_vector_type(4))) float f32x4;

#define TSEQ 2048
#define HDIM 3584
#define NQH  16
#define NKVH 8
#define DH   256
#define WIN  1024
#define QKD  (NQH * DH)   /* 4096 */
#define KVD  (NKVH * DH)  /* 2048 */
#define QLD  8256         /* qkv row stride */
#define OLD  4160         /* o_bf row stride */
#define WOLD 4160         /* WoT row stride */
#define VLD  2112         /* vT row stride */

#define MFMA __builtin_amdgcn_mfma_f32_16x16x32_bf16

__device__ __forceinline__ void gload_lds16(const void* g, void* l) {
  __builtin_amdgcn_global_load_lds(
      (const __attribute__((address_space(1))) void*)g,
      (__attribute__((address_space(3))) void*)l, 16, 0, 0);
}

// ---------------- prep: transposes + hs cvt + rope tables, one launch ----------------
// blocks [0,10752): transpose fp32 RxC -> bf16 CxR (64x64 tiles)
// blocks [10752,14336): hs fp32 -> bf16 (2048 elems/block)
// blocks [14336,15360): rope cos/sin tables (256 entries/block)
__global__ void prep_kernel(const float* __restrict__ hs,
                            const float* __restrict__ Wq,
                            const float* __restrict__ Wk,
                            const float* __restrict__ Wv,
                            const float* __restrict__ Wo,
                            const int* __restrict__ positions,
                            __bf16* __restrict__ hs_bf,
                            __bf16* __restrict__ WqT,
                            __bf16* __restrict__ WkT,
                            __bf16* __restrict__ WvT,
                            __bf16* __restrict__ WoT,
                            float* __restrict__ ct,
                            float* __restrict__ st) {
  __shared__ float tile[64][65];
  int id = blockIdx.x;
  const int tid = threadIdx.x;  // 256
  if (id >= 14336) {            // rope tables
    int i = (id - 14336) * 256 + tid;  // [0, TSEQ*128)
    int t = i >> 7, j = i & 127;
    float invf = (float)exp((double)(-2 * j) * (9.210340371976184 / 256.0));
    float ang = (float)positions[t] * invf;
    ct[i] = cosf(ang);
    st[i] = sinf(ang);
    return;
  }
  if (id >= 10752) {            // hs convert
    long base = (long)(id - 10752) * 2048 + tid * 8;
    float4 v0 = *reinterpret_cast<const float4*>(hs + base);
    float4 v1 = *reinterpret_cast<const float4*>(hs + base + 4);
    bf16x8 o8;
    o8[0] = (__bf16)v0.x; o8[1] = (__bf16)v0.y; o8[2] = (__bf16)v0.z; o8[3] = (__bf16)v0.w;
    o8[4] = (__bf16)v1.x; o8[5] = (__bf16)v1.y; o8[6] = (__bf16)v1.z; o8[7] = (__bf16)v1.w;
    *reinterpret_cast<bf16x8*>(hs_bf + base) = o8;
    return;
  }
  const float* src; __bf16* dst; int C, ldo;
  if (id < 3584)      { src = Wq; dst = WqT; C = QKD; ldo = HDIM; }
  else if (id < 5376) { id -= 3584; src = Wk; dst = WkT; C = KVD; ldo = HDIM; }
  else if (id < 7168) { id -= 5376; src = Wv; dst = WvT; C = KVD; ldo = HDIM; }
  else                { id -= 7168; src = Wo; dst = WoT; C = HDIM; ldo = WOLD; }
  const int nbx = C >> 6;
  const int c0 = (id % nbx) * 64, r0 = (id / nbx) * 64;
#pragma unroll
  for (int it = 0; it < 4; ++it) {
    int f = tid + it * 256;
    int row = f >> 4, c4 = (f & 15) * 4;
    float4 v = *reinterpret_cast<const float4*>(&src[(size_t)(r0 + row) * C + c0 + c4]);
    tile[row][c4] = v.x; tile[row][c4 + 1] = v.y;
    tile[row][c4 + 2] = v.z; tile[row][c4 + 3] = v.w;
  }
  __syncthreads();
#pragma unroll
  for (int it = 0; it < 2; ++it) {
    int s = tid + it * 256;
    int oc = s >> 3, rb = (s & 7) * 8;
    bf16x8 o8;
#pragma unroll
    for (int j = 0; j < 8; ++j) o8[j] = (__bf16)tile[rb + j][oc];
    *reinterpret_cast<bf16x8*>(&dst[(size_t)(c0 + oc) * ldo + r0 + rb]) = o8;
  }
}

// ---------------- 256x256 8-phase GEMM + fused rope/vT epilogue ----------------
// Each block owns one head (col0>>8): 0-15 q (rope, x1/16), 16-23 k (rope),
// 24-31 v (write V^T directly). Epilogue round-trips the C-tile through the
// dead staging LDS.

__device__ __forceinline__ void stage_half(const __bf16* __restrict__ gbase,
                                           int row0, int ldg, int k0,
                                           __bf16* lds_half, int tid) {
  const int lane = tid & 63;
  const int w = tid >> 6;
  const int lr = lane >> 3;                    // row&7 within half
  const int swzcol = ((lane & 7) ^ lr) << 3;   // pre-swizzled source column
  const __bf16* g = gbase + (size_t)(row0 + w * 8 + lr) * ldg + k0 + swzcol;
  __bf16* l = lds_half + w * 512;              // wave-uniform dest (elements)
  gload_lds16(g, l);
  gload_lds16(g + (size_t)64 * ldg, l + 4096);
}

#define BAR __builtin_amdgcn_s_barrier()

#define RD_A(DST, BASE, MO)                                         \
  _Pragma("unroll")                                                 \
  for (int m_ = 0; m_ < 4; ++m_) {                                  \
    const __bf16* p_ = (BASE) + (((MO) + m_) * 16 + l15) * 64;      \
    DST[m_][0] = *(const bf16x8*)(p_ + kxa);                        \
    DST[m_][1] = *(const bf16x8*)(p_ + kxb);                        \
  }

#define RD_B(DST, BASE, NO)                                         \
  _Pragma("unroll")                                                 \
  for (int n_ = 0; n_ < 2; ++n_) {                                  \
    const __bf16* p_ = (BASE) + (bro + ((NO) + n_) * 16 + l15) * 64;\
    DST[n_][0] = *(const bf16x8*)(p_ + kxa);                        \
    DST[n_][1] = *(const bf16x8*)(p_ + kxb);                        \
  }

#define MQUAD(AF, BF, MO, NO)                                          \
  __builtin_amdgcn_s_setprio(1);                                       \
  _Pragma("unroll")                                                    \
  for (int m_ = 0; m_ < 4; ++m_)                                       \
    _Pragma("unroll")                                                  \
    for (int n_ = 0; n_ < 2; ++n_) {                                   \
      acc[(MO) + m_][(NO) + n_] =                                      \
          MFMA(AF[m_][0], BF[n_][0], acc[(MO) + m_][(NO) + n_], 0, 0, 0); \
      acc[(MO) + m_][(NO) + n_] =                                      \
          MFMA(AF[m_][1], BF[n_][1], acc[(MO) + m_][(NO) + n_], 0, 0, 0); \
    }                                                                  \
  __builtin_amdgcn_s_setprio(0);

#define STG(p, ab, h) (lds + (p) * 32768 + (ab) * 16384 + (h) * 8192)

__global__ __launch_bounds__(512, 1) void gemm256_kernel(
    const __bf16* __restrict__ A, const __bf16* __restrict__ B,
    __bf16* __restrict__ C, __bf16* __restrict__ vt,
    const float* __restrict__ ct, const float* __restrict__ st,
    int lda, int Klen, int ldc, int nrc) {
  __shared__ __bf16 lds[67584];  // staging 64K elems; epilogue up to 256x264

  const int nwg = gridDim.x;
  const int per = nwg >> 3;
  const int wg = (blockIdx.x & 7) * per + (blockIdx.x >> 3);  // XCD chunk swizzle
  const int rem = wg % nrc;
  const int row0 = (rem & 7) * 256;        // col-major decode: XCD owns col-band
  const int col0 = (rem >> 3) * 256;

  const int tid = threadIdx.x;
  const int lane = tid & 63, w = tid >> 6;
  const int wr = w >> 2, wc = w & 3;
  const int l15 = lane & 15, lg = lane >> 4;
  const int kxa = (lg * 8) ^ ((lane & 7) << 3);
  const int kxb = (32 + lg * 8) ^ ((lane & 7) << 3);
  const int bro = (wc & 1) * 64;

  const __bf16* Ablk = A + (size_t)row0 * lda;
  const __bf16* Bblk = B + (size_t)col0 * lda;

  const __bf16* Ae = STG(0, 0, wr);
  const __bf16* Be = STG(0, 1, wc >> 1);
  const __bf16* Ao = STG(1, 0, wr);
  const __bf16* Bo = STG(1, 1, wc >> 1);

  f32x4 acc[8][4] = {};
  const int NT = Klen >> 6;
  const int NI = NT >> 1;

  // prologue: tile0 all halves -> buf0; tile1 A halves -> buf1
  stage_half(Ablk, 0,   lda, 0,  STG(0, 0, 0), tid);
  stage_half(Ablk, 128, lda, 0,  STG(0, 0, 1), tid);
  stage_half(Bblk, 0,   lda, 0,  STG(0, 1, 0), tid);
  stage_half(Bblk, 128, lda, 0,  STG(0, 1, 1), tid);
  stage_half(Ablk, 0,   lda, 64, STG(1, 0, 0), tid);
  stage_half(Ablk, 128, lda, 64, STG(1, 0, 1), tid);
  asm volatile("s_waitcnt vmcnt(4)" ::: "memory");
  BAR;

  bf16x8 a03[4][2], a47[4][2], b01[2][2], b23[2][2];

  for (int j = 0; j < NI; ++j) {
    const int e = 2 * j, o = 2 * j + 1;
    const bool last = (j == NI - 1);

    RD_A(a03, Ae, 0);
    RD_B(b01, Be, 0);
    stage_half(Bblk, 0, lda, o * 64, STG(1, 1, 0), tid);
    asm volatile("s_waitcnt lgkmcnt(8)" ::: "memory");
    BAR; MQUAD(a03, b01, 0, 0); BAR;

    RD_A(a47, Ae, 4);
    stage_half(Bblk, 128, lda, o * 64, STG(1, 1, 1), tid);
    BAR; MQUAD(a47, b01, 4, 0); BAR;

    RD_B(b23, Be, 2);
    if (!last) stage_half(Ablk, 0, lda, (e + 2) * 64, STG(0, 0, 0), tid);
    BAR; MQUAD(a47, b23, 4, 2); BAR;

    if (!last) {
      stage_half(Ablk, 128, lda, (e + 2) * 64, STG(0, 0, 1), tid);
      asm volatile("s_waitcnt vmcnt(4)" ::: "memory");
    } else {
      asm volatile("s_waitcnt vmcnt(0)" ::: "memory");
    }
    BAR; MQUAD(a03, b23, 0, 2); BAR;

    RD_A(a03, Ao, 0);
    RD_B(b01, Bo, 0);
    if (!last) stage_half(Bblk, 0, lda, (e + 2) * 64, STG(0, 1, 0), tid);
    asm volatile("s_waitcnt lgkmcnt(8)" ::: "memory");
    BAR; MQUAD(a03, b01, 0, 0); BAR;

    RD_A(a47, Ao, 4);
    if (!last) stage_half(Bblk, 128, lda, (e + 2) * 64, STG(0, 1, 1), tid);
    BAR; MQUAD(a47, b01, 4, 0); BAR;

    RD_B(b23, Bo, 2);
    if (!last) stage_half(Ablk, 0, lda, (o + 2) * 64, STG(1, 0, 0), tid);
    BAR; MQUAD(a47, b23, 4, 2); BAR;

    if (!last) {
      stage_half(Ablk, 128, lda, (o + 2) * 64, STG(1, 0, 1), tid);
      asm volatile("s_waitcnt vmcnt(4)" ::: "memory");
    }
    BAR; MQUAD(a03, b23, 0, 2); BAR;
  }

  // ---- fused epilogue (staging LDS is dead after final BAR) ----
  const int head = col0 >> 8;
  if (head < 24) {
    // q/k: rope via (d, d+128) pairing across waves
    const float scale = (head < 16) ? 0.0625f : 1.0f;
#pragma unroll
    for (int m = 0; m < 8; ++m)
#pragma unroll
      for (int n = 0; n < 4; ++n)
#pragma unroll
        for (int r = 0; r < 4; ++r) {
          int rw = wr * 128 + m * 16 + lg * 4 + r;
          int cl = wc * 64 + n * 16 + l15;
          lds[rw * 256 + cl] = (__bf16)acc[m][n][r];
        }
    __syncthreads();
#pragma unroll
    for (int it8 = 0; it8 < 8; ++it8) {
      int g = it8 * 512 + tid;           // 256 rows x 16 d-groups
      int rw = g >> 4, d0 = (g & 15) * 8;
      bf16x8 x1 = *reinterpret_cast<const bf16x8*>(&lds[rw * 256 + d0]);
      bf16x8 x2 = *reinterpret_cast<const bf16x8*>(&lds[rw * 256 + 128 + d0]);
      int t = row0 + rw;
      const float* cp = ct + t * 128 + d0;
      const float* sp = st + t * 128 + d0;
      bf16x8 o1, o2;
#pragma unroll
      for (int e2 = 0; e2 < 8; ++e2) {
        float c = cp[e2], s = sp[e2];
        float a = (float)x1[e2], b = (float)x2[e2];
        o1[e2] = (__bf16)((a * c - b * s) * scale);
        o2[e2] = (__bf16)((b * c + a * s) * scale);
      }
      *reinterpret_cast<bf16x8*>(&C[(size_t)t * ldc + col0 + d0]) = o1;
      *reinterpret_cast<bf16x8*>(&C[(size_t)t * ldc + col0 + 128 + d0]) = o2;
    }
  } else {
    // v: write V^T directly (store tile transposed in LDS, [256][264])
#pragma unroll
    for (int m = 0; m < 8; ++m)
#pragma unroll
      for (int n = 0; n < 4; ++n)
#pragma unroll
        for (int r = 0; r < 4; ++r) {
          int rw = wr * 128 + m * 16 + lg * 4 + r;
          int cl = wc * 64 + n * 16 + l15;
          lds[cl * 264 + rw] = (__bf16)acc[m][n][r];
        }
    __syncthreads();
    const int vbase = (head - 24) * 256;
#pragma unroll
    for (int it16 = 0; it16 < 16; ++it16) {
      int g = it16 * 512 + tid;          // 256 d x 32 row-groups
      int d = g >> 5, rg = (g & 31) * 8;
      bf16x8 v8 = *reinterpret_cast<const bf16x8*>(&lds[d * 264 + rg]);
      *reinterpret_cast<bf16x8*>(&vt[(size_t)(vbase + d) * VLD + row0 + rg]) = v8;
    }
  }
}

// ---------------- 128x256 lockstep-K GEMM (out-projection) ----------------
__global__ __launch_bounds__(512, 1) void gemm128_kernel(
    const __bf16* __restrict__ A, const __bf16* __restrict__ B,
    float* __restrict__ C, int lda, int Klen, int ldc) {
  __shared__ __bf16 lds[2][3][8192];  // [parity][0=A,1..2=B-halves][128*64]

  const int per = gridDim.x >> 3;
  const int wg = (blockIdx.x & 7) * per + (blockIdx.x >> 3);
  const int row0 = (wg & 15) * 128;
  const int col0 = (wg >> 4) * 256;

  const int tid = threadIdx.x;
  const int lane = tid & 63, w = tid >> 6;
  const int wr = w >> 2, wc = w & 3;   // 2M x 4N
  const int l15 = lane & 15, lg = lane >> 4;
  const int kxa = (lg * 8) ^ ((lane & 7) << 3);
  const int kxb = (32 + lg * 8) ^ ((lane & 7) << 3);
  const int bro = (wc & 1) * 64;

  const __bf16* Ablk = A + (size_t)row0 * lda;
  const __bf16* Bblk = B + (size_t)col0 * lda;

  f32x4 acc[4][4] = {};
  const int NT = Klen >> 6;

  stage_half(Ablk, 0,   lda, 0,  &lds[0][0][0], tid);
  stage_half(Bblk, 0,   lda, 0,  &lds[0][1][0], tid);
  stage_half(Bblk, 128, lda, 0,  &lds[0][2][0], tid);
  stage_half(Ablk, 0,   lda, 64, &lds[1][0][0], tid);
  asm volatile("s_waitcnt vmcnt(2)" ::: "memory");
  BAR;

  bf16x8 a03[4][2], b01[2][2], b23[2][2];

  for (int t = 0; t < NT; ++t) {
    const int cur = t & 1, nxt = cur ^ 1;
    const __bf16* Ah = &lds[cur][0][0];
    const __bf16* Bh = &lds[cur][1 + (wc >> 1)][0];

    {
      const int MO = wr * 4;
#pragma unroll
      for (int m_ = 0; m_ < 4; ++m_) {
        const __bf16* p_ = Ah + ((MO + m_) * 16 + l15) * 64;
        a03[m_][0] = *(const bf16x8*)(p_ + kxa);
        a03[m_][1] = *(const bf16x8*)(p_ + kxb);
      }
    }
    RD_B(b01, Bh, 0);
    RD_B(b23, Bh, 2);

    if (t + 1 < NT) {
      stage_half(Bblk, 0,   lda, (t + 1) * 64, &lds[nxt][1][0], tid);
      stage_half(Bblk, 128, lda, (t + 1) * 64, &lds[nxt][2][0], tid);
    }

    asm volatile("s_waitcnt lgkmcnt(0)" ::: "memory");
    BAR;
    if (t + 2 < NT) stage_half(Ablk, 0, lda, (t + 2) * 64, &lds[cur][0][0], tid);

    __builtin_amdgcn_s_setprio(1);
#pragma unroll
    for (int m_ = 0; m_ < 4; ++m_) {
#pragma unroll
      for (int n_ = 0; n_ < 2; ++n_) {
        acc[m_][n_] = MFMA(a03[m_][0], b01[n_][0], acc[m_][n_], 0, 0, 0);
        acc[m_][n_] = MFMA(a03[m_][1], b01[n_][1], acc[m_][n_], 0, 0, 0);
        acc[m_][n_ + 2] = MFMA(a03[m_][0], b23[n_][0], acc[m_][n_ + 2], 0, 0, 0);
        acc[m_][n_ + 2] = MFMA(a03[m_][1], b23[n_][1], acc[m_][n_ + 2], 0, 0, 0);
      }
    }
    __builtin_amdgcn_s_setprio(0);

    if (t + 2 < NT) {
      asm volatile("s_waitcnt vmcnt(2)" ::: "memory");
    } else {
      asm volatile("s_waitcnt vmcnt(0)" ::: "memory");
    }
    BAR;
  }

#pragma unroll
  for (int m = 0; m < 4; ++m)
#pragma unroll
    for (int n = 0; n < 4; ++n)
#pragma unroll
      for (int r = 0; r < 4; ++r) {
        int row = row0 + wr * 64 + m * 16 + lg * 4 + r;
        int col = col0 + wc * 64 + n * 16 + l15;
        C[(size_t)row * ldc + col] = acc[m][n][r];
      }
}

// ---------------- flash attention: 4-wave blocks, 2 blocks/CU ----------------
__device__ __forceinline__ void attn_stage(const __bf16* __restrict__ kg,
                                           const __bf16* __restrict__ vg,
                                           __bf16* Kd, __bf16* Vd, int tid) {
#pragma unroll
  for (int i = 0; i < 8; ++i) {
    int c = tid + i * 256;
    int krow = c >> 5, kslot = c & 31;             // K: [64 keys][256 d]
    gload_lds16(kg + (size_t)krow * QLD + ((kslot ^ (krow & 7)) * 8), Kd + c * 8);
    int vrow = c >> 3, vslot = c & 7;              // V: [256 d][64 keys]
    gload_lds16(vg + (size_t)vrow * VLD + ((vslot ^ (vrow & 7)) * 8), Vd + c * 8);
  }
}

__global__ __launch_bounds__(256, 2) void attn_kernel(
    const __bf16* __restrict__ q, const __bf16* __restrict__ k,
    const __bf16* __restrict__ vt, __bf16* __restrict__ o) {
  __shared__ __bf16 Klds[64][256];   // [key][d], slot-swizzled
  __shared__ __bf16 Vlds[256][64];   // [d][key], slot-swizzled
  __shared__ __bf16 Plds[4][16][72]; // [wave][row][key+pad]

  const int tid = threadIdx.x;
  const int wave = tid >> 6;
  const int lane = tid & 63;
  const int l16 = lane & 15;
  const int lg = lane >> 4;
  const int h = blockIdx.x;                      // kv-head == XCD (id%8)
  const int qh = 2 * h + (blockIdx.y & 1);
  const int q0 = (31 - (int)(blockIdx.y >> 1)) << 6;  // LPT: big windows first
  const int qr = q0 + wave * 16;

  const __bf16* kg0 = k + (size_t)h * DH;
  const __bf16* vg0 = vt + (size_t)(h * DH) * VLD;

  int t_lo = q0 - (WIN - 1);
  if (t_lo < 0) t_lo = 0;
  t_lo &= ~63;
  const int NTile = ((q0 - t_lo) >> 6) + 1;

  bf16x8 qf[8];
  {
    const __bf16* qp = q + (size_t)(qr + l16) * QLD + qh * DH + lg * 8;
#pragma unroll
    for (int ds = 0; ds < 8; ++ds)
      qf[ds] = *reinterpret_cast<const bf16x8*>(qp + ds * 32);
  }

  f32x4 accO[16] = {};
  float l_run[4] = {0.f, 0.f, 0.f, 0.f};

  for (int it = 0; it < NTile; ++it) {
    const int t0 = t_lo + it * 64;

    attn_stage(kg0 + (size_t)t0 * QLD, vg0 + t0, &Klds[0][0], &Vlds[0][0], tid);
    asm volatile("s_waitcnt vmcnt(0)" ::: "memory");
    __builtin_amdgcn_s_barrier();

    // QK^T
    f32x4 accS[4] = {};
    __builtin_amdgcn_s_setprio(1);
#pragma unroll
    for (int ds = 0; ds < 8; ++ds)
#pragma unroll
      for (int nt = 0; nt < 4; ++nt) {
        int row = nt * 16 + l16;
        int slot = (4 * ds + lg) ^ (l16 & 7);
        bf16x8 kf = *reinterpret_cast<const bf16x8*>(&Klds[0][0] + row * 256 + slot * 8);
        accS[nt] = MFMA(qf[ds], kf, accS[nt], 0, 0, 0);
      }
    __builtin_amdgcn_s_setprio(0);

    // softcap+exp fixed-max, mask, P -> LDS, row-sum
    float rs[4] = {0.f, 0.f, 0.f, 0.f};
#pragma unroll
    for (int nt = 0; nt < 4; ++nt) {
      int key = t0 + nt * 16 + l16;
#pragma unroll
      for (int r = 0; r < 4; ++r) {
        int row = qr + lg * 4 + r;
        float t = __expf(accS[nt][r] * 0.04f);
        float p = __expf(-100.0f / (t + 1.0f));
        bool valid = (key <= row) && (row - key < WIN);
        p = valid ? p : 0.f;
        rs[r] += p;
        Plds[wave][lg * 4 + r][nt * 16 + l16] = (__bf16)p;
      }
    }
#pragma unroll
    for (int off = 1; off < 16; off <<= 1)
#pragma unroll
      for (int r = 0; r < 4; ++r)
        rs[r] += __shfl_xor(rs[r], off);
#pragma unroll
    for (int r = 0; r < 4; ++r)
      l_run[r] += rs[r];

    // PV
    __builtin_amdgcn_s_setprio(1);
#pragma unroll
    for (int ks = 0; ks < 2; ++ks) {
      bf16x8 pa = *reinterpret_cast<const bf16x8*>(&Plds[wave][l16][ks * 32 + lg * 8]);
#pragma unroll
      for (int nt2 = 0; nt2 < 16; ++nt2) {
        int row = nt2 * 16 + l16;
        int slot = (4 * ks + lg) ^ (l16 & 7);
        bf16x8 vb = *reinterpret_cast<const bf16x8*>(&Vlds[0][0] + row * 64 + slot * 8);
        accO[nt2] = MFMA(pa, vb, accO[nt2], 0, 0, 0);
      }
    }
    __builtin_amdgcn_s_setprio(0);
    __builtin_amdgcn_s_barrier();  // all reads done before next tile's DMA
  }

#pragma unroll
  for (int r = 0; r < 4; ++r) {
    float inv_l = 1.f / l_run[r];
    int row = qr + lg * 4 + r;
#pragma unroll
    for (int nt2 = 0; nt2 < 16; ++nt2)
      o[(size_t)row * OLD + qh * DH + nt2 * 16 + l16] = (__bf16)(accO[nt2][r] * inv_l);
  }
}

// ---------------- launcher ----------------

extern "C" void kernel_launch(void* const* d_in, const int* in_sizes, int n_in,
                              void* d_out, int out_size, void* d_ws, size_t ws_size,
                              hipStream_t stream) {
  const float* hs = (const float*)d_in[0];
  const float* Wq = (const float*)d_in[1];
  const float* Wk = (const float*)d_in[2];
  const float* Wv = (const float*)d_in[3];
  const float* Wo = (const float*)d_in[4];
  const int* positions = (const int*)d_in[5];
  float* out = (float*)d_out;

  char* ws = (char*)d_ws;
  const size_t SZ_HS  = (size_t)TSEQ * HDIM * 2;
  const size_t SZ_WQT = (size_t)QKD * HDIM * 2;
  const size_t SZ_WKT = (size_t)KVD * HDIM * 2;
  const size_t SZ_WOT = (size_t)HDIM * WOLD * 2;
  const size_t SZ_QKV = (size_t)TSEQ * QLD * 2;
  const size_t SZ_O   = (size_t)TSEQ * OLD * 2;
  const size_t SZ_VT  = (size_t)KVD * VLD * 2;
  const size_t SZ_TBL = (size_t)TSEQ * 128 * 4;

  __bf16* hs_bf = (__bf16*)ws; ws += SZ_HS;
  __bf16* WqT   = (__bf16*)ws; ws += SZ_WQT;   // WqT/WkT/WvT contiguous -> fused B
  __bf16* WkT   = (__bf16*)ws; ws += SZ_WKT;
  __bf16* WvT   = (__bf16*)ws; ws += SZ_WKT;
  __bf16* WoT   = (__bf16*)ws; ws += SZ_WOT;
  __bf16* qkv   = (__bf16*)ws; ws += SZ_QKV;
  __bf16* o_bf  = (__bf16*)ws; ws += SZ_O;
  __bf16* vt_bf = (__bf16*)ws; ws += SZ_VT;
  float*  cost  = (float*)ws;  ws += SZ_TBL;
  float*  sint  = (float*)ws;  ws += SZ_TBL;
  if ((size_t)(ws - (char*)d_ws) > ws_size) return;

  // prep: weight transposes + hs cvt + rope tables (one launch)
  prep_kernel<<<15360, 256, 0, stream>>>(hs, Wq, Wk, Wv, Wo, positions, hs_bf,
                                         WqT, WkT, WvT, WoT, cost, sint);

  // fused QKV projection + rope(q,k) + V^T epilogue: 256 blocks (1/CU)
  gemm256_kernel<<<256, 512, 0, stream>>>(hs_bf, WqT, qkv, vt_bf, cost, sint,
                                          HDIM, HDIM, QLD, 256);

  // attention: 512 blocks, 2/CU; grid.x = kv-head = XCD
  attn_kernel<<<dim3(NKVH, 64), 256, 0, stream>>>(qkv, qkv + QKD, vt_bf, o_bf);

  // output projection: 128x256 tiles, 224 blocks, lockstep K, fp32 direct out
  gemm128_kernel<<<224, 512, 0, stream>>>(o_bf, WoT, out, OLD, QKD, HDIM);
}